// Round 11
// baseline (814.294 us; speedup 1.0000x reference)
//
#include <hip/hip_runtime.h>
#include <stdint.h>

using u16 = unsigned short;
typedef __attribute__((ext_vector_type(8))) __bf16 bf16x8;
typedef __attribute__((ext_vector_type(4))) float f32x4;

#define DEV __device__ __forceinline__

static constexpr int kB = 4, kL = 4096, kD = 1024, kFF = 4096;
static constexpr int kM = kB * kL;
static constexpr int kLC = 256, kNC = kL / kLC;
static constexpr float kEPS = 1e-6f;

DEV u16 f2bf(float v) {
  union { float f; uint32_t u; } x; x.f = v;
  uint32_t r = x.u + 0x7FFFu + ((x.u >> 16) & 1u);  // RNE
  return (u16)(r >> 16);
}
DEV float bf2f(u16 u) {
  union { uint32_t u; float f; } x; x.u = (uint32_t)u << 16; return x.f;
}
DEV float sigm(float x) { return 1.0f / (1.0f + __expf(-x)); }

DEV void gload_lds16(const void* g, void* l) {
  __builtin_amdgcn_global_load_lds(
      (const __attribute__((address_space(1))) void*)g,
      (__attribute__((address_space(3))) void*)l, 16, 0, 0);
}

// inline-asm LDS read: opaque to the compiler's alias analysis, so no
// conservative vmcnt(0) ordering vs in-flight global_load_lds (r10 theory).
typedef __attribute__((address_space(3))) const u16* lds_cp;
DEV bf16x8 ds_read128(lds_cp p) {
  bf16x8 r;
  asm volatile("ds_read_b128 %0, %1" : "=v"(r) : "v"(p));
  return r;
}

// ---------------- weight transpose + f32->bf16: out[n*K+k] = bf16(in[k*N+n])
__global__ __launch_bounds__(256) void wtrans_kernel(const float* __restrict__ in,
                                                     u16* __restrict__ out,
                                                     int K, int N) {
  __shared__ float t[32][33];
  const int n0 = blockIdx.x * 32, k0 = blockIdx.y * 32;
  const int tx = threadIdx.x, ty = threadIdx.y;
#pragma unroll
  for (int i = 0; i < 4; ++i)
    t[ty + i * 8][tx] = in[(size_t)(k0 + ty + i * 8) * N + (n0 + tx)];
  __syncthreads();
#pragma unroll
  for (int i = 0; i < 4; ++i)
    out[(size_t)(n0 + ty + i * 8) * K + (k0 + tx)] = f2bf(t[tx][ty + i * 8]);
}

// paired transpose: out rows interleave a and b in 32-col groups.
__global__ __launch_bounds__(256) void wtrans_pair(const float* __restrict__ a,
                                                   const float* __restrict__ b,
                                                   u16* __restrict__ out,
                                                   int K, int Ncols) {
  __shared__ float t[32][33];
  const int n0 = blockIdx.x * 32, k0 = blockIdx.y * 32;
  const int sel = (n0 >> 5) & 1;
  const int c0 = (n0 >> 6) * 32;
  const float* __restrict__ src = sel ? b : a;
  const int tx = threadIdx.x, ty = threadIdx.y;
#pragma unroll
  for (int i = 0; i < 4; ++i)
    t[ty + i * 8][tx] = src[(size_t)(k0 + ty + i * 8) * Ncols + (c0 + tx)];
  __syncthreads();
#pragma unroll
  for (int i = 0; i < 4; ++i)
    out[(size_t)(n0 + ty + i * 8) * K + (k0 + tx)] = f2bf(t[tx][ty + i * 8]);
}

// ---------------- RMSNorm (f32 in, bf16 out), one block per row, D=1024
__global__ __launch_bounds__(256) void rmsnorm_kernel(const float* __restrict__ x,
                                                      const float* __restrict__ g,
                                                      u16* __restrict__ out) {
  const int row = blockIdx.x;
  const int t = threadIdx.x;
  const float4 v = ((const float4*)(x + (size_t)row * kD))[t];
  float ss = v.x * v.x + v.y * v.y + v.z * v.z + v.w * v.w;
#pragma unroll
  for (int o = 1; o < 64; o <<= 1) ss += __shfl_xor(ss, o, 64);
  __shared__ float red[4];
  if ((t & 63) == 0) red[t >> 6] = ss;
  __syncthreads();
  const float tot = red[0] + red[1] + red[2] + red[3];
  const float sc = rsqrtf(tot * (1.0f / kD) + kEPS);
  const float4 gv = ((const float4*)g)[t];
  const uint32_t lo = (uint32_t)f2bf(v.x * sc * gv.x) | ((uint32_t)f2bf(v.y * sc * gv.y) << 16);
  const uint32_t hi = (uint32_t)f2bf(v.z * sc * gv.z) | ((uint32_t)f2bf(v.w * sc * gv.w) << 16);
  *(uint2*)(out + (size_t)row * kD + t * 4) = make_uint2(lo, hi);
}

// ---------------- 256x128 lockstep 3-phase GEMM, BK=32 (r10 geometry).
// THIS ROUND'S SINGLE CHANGE: LDS hazards made compiler-invisible/explicit —
// (a) fragment reads are inline-asm ds_read_b128 (no conservative vmcnt(0)
//     ordering vs outstanding global_load_lds),
// (b) __builtin_amdgcn_s_barrier() instead of raw asm barrier,
// (c) sched_barrier(0) after each lgkmcnt(0) (rule #18: MFMA hoist fence).
// Schedule, swizzle (r9-verified 0-conflict), ring-stage ledger, raster,
// epilogues, host code: byte-identical to round 10.
template <int MODE>
__global__ __launch_bounds__(256, 2) void gemm256(
    const u16* __restrict__ A, const u16* __restrict__ Bt,
    const float* __restrict__ bias, const float* __restrict__ bias2,
    const u16* __restrict__ aux, int auxld,
    const float* __restrict__ res, float* __restrict__ Cf,
    u16* __restrict__ Cb, float* __restrict__ C2,
    int M, int N, int K) {
  __shared__ u16 sm[24576];  // 48 KiB: 2 slots x (A[256][32] 16K + B[128][32] 8K)
  const int tid = threadIdx.x;
  const int lane = tid & 63;
  const int wave = tid >> 6;                // 0..3
  const int wr = wave >> 1, wc = wave & 1;  // 2M x 2N wave grid

  // bijective XCD swizzle (m204) + supertile raster (n-group 4, m fastest)
  const int gx = gridDim.x;
  const int nwg = gx * gridDim.y;
  const int bid = blockIdx.y * gx + blockIdx.x;
  const int q = nwg >> 3, r = nwg & 7;
  const int xcd = bid & 7, idx0 = bid >> 3;
  const int wg = (xcd < r ? xcd * (q + 1) : r * (q + 1) + (xcd - r) * q) + idx0;
  const int per = gridDim.y * 4;
  const int sg = wg / per, srem = wg % per;
  const int m0 = (srem >> 2) * 256;
  const int n0 = (sg * 4 + (srem & 3)) * 128;

  const int NK = K >> 5;

  // staging: linear LDS dest (tid*16B), inverse-swizzled global source.
  const int rsub = tid >> 2;
  const int kel = ((tid & 3) ^ ((tid >> 3) & 3)) * 8;
  const size_t srcA = (size_t)(m0 + rsub) * K + kel;
  const size_t srcB = (size_t)(n0 + rsub) * K + kel;

  auto stageA = [&](int kt) {
    u16* d = sm + (kt & 1) * 12288 + tid * 8;
    const u16* s = A + srcA + (size_t)kt * 32;
#pragma unroll
    for (int j = 0; j < 4; ++j)
      gload_lds16(s + (size_t)(j * 64) * K, d + j * 2048);  // rows +0,64,128,192
  };
  auto stageB = [&](int kt) {
    u16* d = sm + (kt & 1) * 12288 + 8192 + tid * 8;
    const u16* s = Bt + srcB + (size_t)kt * 32;
    gload_lds16(s, d);                                 // rows 0-63
    gload_lds16(s + (size_t)64 * K, d + 2048);         // rows 64-127
  };

  // fragment read: row-local ra=lane&15, kq=lane>>4;
  // u16 off = ra*32 + 8*(kq ^ ((ra>>1)&3)); all frag-row offsets are 0 mod 8.
  const int ra = lane & 15;
  const int rb = ra * 32 + ((((lane >> 4) ^ (ra >> 1)) & 3) << 3);

  f32x4 acc[8][4] = {};
  bf16x8 af[8], bf[4];

  // prologue: tiles 0,1 staged (6 loads each); vmcnt(6) -> tile0 landed
  stageA(0); stageB(0);
  if (NK > 1) { stageA(1); stageB(1); }
  asm volatile("s_waitcnt vmcnt(6)");
  __builtin_amdgcn_s_barrier();

  for (int h = 0; h < NK; ++h) {
    lds_cp Az = (lds_cp)(sm + (h & 1) * 12288 + wr * 4096);          // wr*128 rows
    lds_cp Bz = (lds_cp)(sm + (h & 1) * 12288 + 8192 + wc * 2048);   // wc*64 rows

    // ---- Phase 1: read af[0..7] + bf[0..1]; MFMA ni 0-1 (16)
#pragma unroll
    for (int mi = 0; mi < 8; ++mi) af[mi] = ds_read128(Az + mi * 512 + rb);
    bf[0] = ds_read128(Bz + rb);
    bf[1] = ds_read128(Bz + 512 + rb);
    __builtin_amdgcn_s_barrier();
    asm volatile("s_waitcnt lgkmcnt(0)");
    __builtin_amdgcn_sched_barrier(0);
    __builtin_amdgcn_s_setprio(1);
#pragma unroll
    for (int mi = 0; mi < 8; ++mi)
#pragma unroll
      for (int ni = 0; ni < 2; ++ni)
        acc[mi][ni] = __builtin_amdgcn_mfma_f32_16x16x32_bf16(af[mi], bf[ni], acc[mi][ni], 0, 0, 0);
    __builtin_amdgcn_s_setprio(0);
    __builtin_amdgcn_s_barrier();

    // ---- Phase 2: read bf[2..3]; stage A(h+2) [A reads certified ph1-end]; MFMA ni 2
    bf[2] = ds_read128(Bz + 1024 + rb);
    bf[3] = ds_read128(Bz + 1536 + rb);
    if (h + 2 < NK) stageA(h + 2);
    __builtin_amdgcn_s_barrier();
    asm volatile("s_waitcnt lgkmcnt(0)");
    __builtin_amdgcn_sched_barrier(0);
    __builtin_amdgcn_s_setprio(1);
#pragma unroll
    for (int mi = 0; mi < 8; ++mi)
      acc[mi][2] = __builtin_amdgcn_mfma_f32_16x16x32_bf16(af[mi], bf[2], acc[mi][2], 0, 0, 0);
    __builtin_amdgcn_s_setprio(0);
    __builtin_amdgcn_s_barrier();

    // ---- Phase 3: stage B(h+2) [B reads certified ph2-end]; MFMA ni 3; vmcnt
    if (h + 2 < NK) stageB(h + 2);
    __builtin_amdgcn_s_setprio(1);
#pragma unroll
    for (int mi = 0; mi < 8; ++mi)
      acc[mi][3] = __builtin_amdgcn_mfma_f32_16x16x32_bf16(af[mi], bf[3], acc[mi][3], 0, 0, 0);
    __builtin_amdgcn_s_setprio(0);
    if (h + 2 < NK) asm volatile("s_waitcnt vmcnt(6)");  // tile h+1 landed
    else            asm volatile("s_waitcnt vmcnt(0)");  // tail: full drain
    __builtin_amdgcn_s_barrier();
  }

  // ---- epilogue. C/D layout: col = lane&15, row = (lane>>4)*4 + j
  const int ca = ra;
  const int rq = (lane >> 4) * 4;
  if (MODE == 6 || MODE == 7) {
    const int Nout = N >> 1;
#pragma unroll
    for (int mi = 0; mi < 8; ++mi) {
#pragma unroll
      for (int ni = 0; ni < 2; ++ni) {
        const int cout = (n0 >> 1) + wc * 32 + ni * 16 + ca;
        const float b1 = bias[cout], b2 = bias2[cout];
#pragma unroll
        for (int j = 0; j < 4; ++j) {
          const int rr = m0 + wr * 128 + mi * 16 + rq + j;
          const size_t idx = (size_t)rr * Nout + cout;
          const float v1 = acc[mi][ni][j] + b1;
          const float v2 = acc[mi][2 + ni][j] + b2;
          if (MODE == 7) {
            Cf[idx] = sigm(-v2);              // decay A
            C2[idx] = sigm(v1) * sigm(v2);    // input B
          } else {
            Cb[idx] = f2bf(v2 * (v1 * sigm(v1)));  // fc * silu(fca)
          }
        }
      }
    }
  } else {
#pragma unroll
    for (int mi = 0; mi < 8; ++mi) {
#pragma unroll
      for (int ni = 0; ni < 4; ++ni) {
        const int c = n0 + wc * 64 + ni * 16 + ca;
        const float bz = bias[c];
#pragma unroll
        for (int j = 0; j < 4; ++j) {
          const int rr = m0 + wr * 128 + mi * 16 + rq + j;
          const size_t idx = (size_t)rr * N + c;
          const float v = acc[mi][ni][j] + bz;
          if (MODE == 2) {
            const float a = bf2f(aux[(size_t)rr * auxld + c]);
            Cf[idx] = v * (a * sigm(a)) + res[idx];
          } else if (MODE == 4) {
            Cf[idx] = v + res[idx];
          } else {  // MODE 5
            Cb[idx] = f2bf(v);
          }
        }
      }
    }
  }
}

// ---------------- chunked scan: h[l] = A[l]*h[l-1] + B[l]
__global__ __launch_bounds__(256) void scan_phase1(const float* __restrict__ Aa,
                                                   const float* __restrict__ Bv,
                                                   float* __restrict__ P,
                                                   float* __restrict__ S) {
  const int d = blockIdx.x * 256 + threadIdx.x;
  const int c = blockIdx.y, b = blockIdx.z;
  size_t base = ((size_t)b * kL + (size_t)c * kLC) * kD + d;
  float p = 1.0f, s = 0.0f;
#pragma unroll 4
  for (int l = 0; l < kLC; ++l) {
    const float a = Aa[base];
    const float bv = Bv[base];
    p *= a;
    s = fmaf(a, s, bv);
    base += kD;
  }
  const size_t o = ((size_t)b * kNC + c) * kD + d;
  P[o] = p; S[o] = s;
}

__global__ __launch_bounds__(256) void scan_phase2(const float* __restrict__ P,
                                                   const float* __restrict__ S,
                                                   const float* __restrict__ hidden,
                                                   float* __restrict__ Hini) {
  const int d = blockIdx.x * 256 + threadIdx.x;
  const int b = blockIdx.y;
  float carry = hidden[(size_t)b * kD + d];
  for (int c = 0; c < kNC; ++c) {
    const size_t o = ((size_t)b * kNC + c) * kD + d;
    Hini[o] = carry;
    carry = fmaf(P[o], carry, S[o]);
  }
}

__global__ __launch_bounds__(256) void scan_phase3(const float* __restrict__ Aa,
                                                   const float* __restrict__ Bv,
                                                   const float* __restrict__ Hini,
                                                   float* __restrict__ Hout,
                                                   u16* __restrict__ Hbf) {
  const int d = blockIdx.x * 256 + threadIdx.x;
  const int c = blockIdx.y, b = blockIdx.z;
  float h = Hini[((size_t)b * kNC + c) * kD + d];
  size_t base = ((size_t)b * kL + (size_t)c * kLC) * kD + d;
#pragma unroll 4
  for (int l = 0; l < kLC; ++l) {
    h = fmaf(Aa[base], h, Bv[base]);
    Hout[base] = h;
    Hbf[base] = f2bf(h);
    base += kD;
  }
}

// ---------------- host
extern "C" void kernel_launch(void* const* d_in, const int* in_sizes, int n_in,
                              void* d_out, int out_size, void* d_ws, size_t ws_size,
                              hipStream_t stream) {
  const float* x      = (const float*)d_in[0];
  const float* hidden = (const float*)d_in[1];
  const float* w_ln_z = (const float*)d_in[2];
  const float* b_ln_z = (const float*)d_in[3];
  const float* w_dt   = (const float*)d_in[4];
  const float* b_dt   = (const float*)d_in[5];
  const float* w_y    = (const float*)d_in[6];
  const float* b_y    = (const float*)d_in[7];
  const float* w_yact = (const float*)d_in[8];
  const float* b_yact = (const float*)d_in[9];
  const float* w_fc   = (const float*)d_in[10];
  const float* b_fc   = (const float*)d_in[11];
  const float* w_fca  = (const float*)d_in[12];
  const float* b_fca  = (const float*)d_in[13];
  const float* w_out  = (const float*)d_in[14];
  const float* b_out  = (const float*)d_in[15];
  const float* g_sio  = (const float*)d_in[16];
  const float* g_ffn  = (const float*)d_in[17];

  char* ws = (char*)d_ws;
  const size_t MiB = 1ull << 20;
  u16* wzdT  = (u16*)(ws + 0 * MiB);      // [2048,1024] paired z|dt, 4 MiB
  u16* wyaT  = (u16*)(ws + 4 * MiB);      // 2 MiB
  u16* wyT   = (u16*)(ws + 6 * MiB);      // 2 MiB
  u16* wfgT  = (u16*)(ws + 8 * MiB);      // [8192,1024] paired fca|fc, 16 MiB
  u16* woutT = (u16*)(ws + 24 * MiB);     // [1024,4096] 8 MiB
  u16*   xn    = (u16*)(ws + 33 * MiB);   // [M,D] bf16 32 MiB (reused as xn2)
  u16*   yabuf = (u16*)(ws + 65 * MiB);   // [M,D] bf16 32 MiB
  float* Abuf  = (float*)(ws + 97 * MiB); // [M,D] f32 64 MiB (reused as x1)
  float* Bvbuf = (float*)(ws + 161 * MiB);// [M,D] f32 64 MiB (dead after scan)
  u16*   hbf   = (u16*)(ws + 225 * MiB);  // [M,D] bf16 32 MiB (dead after y-GEMM)
  u16*   Ubuf  = (u16*)(ws + 161 * MiB);  // [M,FF] bf16 128 MiB, overlays dead Bv/hbf
  float* Pbuf  = (float*)(ws + 289 * MiB);
  float* Sbuf  = (float*)(ws + 290 * MiB);
  float* Hini  = (float*)(ws + 291 * MiB);// ends 292 MiB

  float* xout = (float*)d_out;
  float* hout = xout + (size_t)kM * kD;
  float* x1 = Abuf;

  const dim3 tb(32, 8);
  wtrans_pair<<<dim3(2048 / 32, kD / 32), tb, 0, stream>>>(w_ln_z, w_dt, wzdT, kD, kD);
  wtrans_pair<<<dim3(8192 / 32, kD / 32), tb, 0, stream>>>(w_fca, w_fc, wfgT, kD, kFF);
  wtrans_kernel<<<dim3(kD / 32, kD / 32), tb, 0, stream>>>(w_yact, wyaT, kD, kD);
  wtrans_kernel<<<dim3(kD / 32, kD / 32), tb, 0, stream>>>(w_y, wyT, kD, kD);
  wtrans_kernel<<<dim3(kD / 32, kFF / 32), tb, 0, stream>>>(w_out, woutT, kFF, kD);

  rmsnorm_kernel<<<kM, 256, 0, stream>>>(x, g_sio, xn);

  // paired z|dt GEMM -> A = sigm(-dt), Bv = sigm(z)*sigm(dt)
  gemm256<7><<<dim3(2048 / 128, kM / 256), 256, 0, stream>>>(
      xn, wzdT, b_ln_z, b_dt, nullptr, 0, nullptr, Abuf, nullptr, Bvbuf, kM, 2048, kD);
  // ya = xn @ w_y_act + b (bf16)
  gemm256<5><<<dim3(kD / 128, kM / 256), 256, 0, stream>>>(
      xn, wyaT, b_yact, nullptr, nullptr, 0, nullptr, nullptr, yabuf, nullptr, kM, kD, kD);

  scan_phase1<<<dim3(kD / 256, kNC, kB), 256, 0, stream>>>(Abuf, Bvbuf, Pbuf, Sbuf);
  scan_phase2<<<dim3(kD / 256, kB), 256, 0, stream>>>(Pbuf, Sbuf, hidden, Hini);
  scan_phase3<<<dim3(kD / 256, kNC, kB), 256, 0, stream>>>(Abuf, Bvbuf, Hini, hout, hbf);

  // x1 = (h @ w_y + b_y) * silu(ya) + x   (x1 reuses Abuf)
  gemm256<2><<<dim3(kD / 128, kM / 256), 256, 0, stream>>>(
      hbf, wyT, b_y, nullptr, yabuf, kD, x, x1, nullptr, nullptr, kM, kD, kD);

  rmsnorm_kernel<<<kM, 256, 0, stream>>>(x1, g_ffn, xn);

  // paired FFN up+gate: U = fc * silu(fca), full M, in-register gating
  gemm256<6><<<dim3(8192 / 128, kM / 256), 256, 0, stream>>>(
      xn, wfgT, b_fca, b_fc, nullptr, 0, nullptr, nullptr, Ubuf, nullptr, kM, 8192, kD);

  // xout = U @ w_out + b_out + x1  (K=4096)
  gemm256<4><<<dim3(kD / 128, kM / 256), 256, 0, stream>>>(
      Ubuf, woutT, b_out, nullptr, nullptr, 0, x1, xout, nullptr, nullptr, kM, kD, kFF);
}

// Round 12
// 759.100 us; speedup vs baseline: 1.0727x; 1.0727x over previous
//
#include <hip/hip_runtime.h>
#include <stdint.h>

using u16 = unsigned short;
typedef __attribute__((ext_vector_type(8))) __bf16 bf16x8;
typedef __attribute__((ext_vector_type(4))) float f32x4;

#define DEV __device__ __forceinline__

static constexpr int kB = 4, kL = 4096, kD = 1024, kFF = 4096;
static constexpr int kM = kB * kL;
static constexpr int kLC = 256, kNC = kL / kLC;
static constexpr float kEPS = 1e-6f;

DEV u16 f2bf(float v) {
  union { float f; uint32_t u; } x; x.f = v;
  uint32_t r = x.u + 0x7FFFu + ((x.u >> 16) & 1u);  // RNE
  return (u16)(r >> 16);
}
DEV float bf2f(u16 u) {
  union { uint32_t u; float f; } x; x.u = (uint32_t)u << 16; return x.f;
}
DEV float sigm(float x) { return 1.0f / (1.0f + __expf(-x)); }

DEV void gload_lds16(const void* g, void* l) {
  __builtin_amdgcn_global_load_lds(
      (const __attribute__((address_space(1))) void*)g,
      (__attribute__((address_space(3))) void*)l, 16, 0, 0);
}

// ---------------- merged weight transpose + f32->bf16 (all 5 weights, 1 launch)
// single: out[n*K+k] = bf16(in[k*N+n]); pair: out rows interleave a,b in
// 32-col groups (g=n>>6, r=n&63: src = r<32?a:b, col = g*32+(r&31)).
__global__ __launch_bounds__(256) void wtrans_all(
    const float* __restrict__ w_ln_z, const float* __restrict__ w_dt,
    const float* __restrict__ w_fca, const float* __restrict__ w_fc,
    const float* __restrict__ w_yact, const float* __restrict__ w_y,
    const float* __restrict__ w_out_,
    u16* __restrict__ wzdT, u16* __restrict__ wfgT, u16* __restrict__ wyaT,
    u16* __restrict__ wyT, u16* __restrict__ woutT) {
  const int bid = blockIdx.x;
  const float *a, *b; u16* out; int K, Ncols, bx, local; bool pair;
  if (bid < 2048)       { local = bid;         a = w_ln_z; b = w_dt; out = wzdT;  K = 1024; Ncols = 1024; bx = 64;  pair = true;  }
  else if (bid < 10240) { local = bid - 2048;  a = w_fca;  b = w_fc; out = wfgT;  K = 1024; Ncols = 4096; bx = 256; pair = true;  }
  else if (bid < 11264) { local = bid - 10240; a = w_yact; b = nullptr; out = wyaT; K = 1024; Ncols = 1024; bx = 32; pair = false; }
  else if (bid < 12288) { local = bid - 11264; a = w_y;    b = nullptr; out = wyT;  K = 1024; Ncols = 1024; bx = 32; pair = false; }
  else                  { local = bid - 12288; a = w_out_; b = nullptr; out = woutT; K = 4096; Ncols = 1024; bx = 32; pair = false; }
  const int n0 = (local % bx) * 32, k0 = (local / bx) * 32;
  __shared__ float t[32][33];
  const int tx = threadIdx.x, ty = threadIdx.y;
  const float* src; int c0;
  if (pair) { src = ((n0 >> 5) & 1) ? b : a; c0 = (n0 >> 6) * 32; }
  else      { src = a; c0 = n0; }
#pragma unroll
  for (int i = 0; i < 4; ++i)
    t[ty + i * 8][tx] = src[(size_t)(k0 + ty + i * 8) * Ncols + (c0 + tx)];
  __syncthreads();
#pragma unroll
  for (int i = 0; i < 4; ++i)
    out[(size_t)(n0 + ty + i * 8) * K + (k0 + tx)] = f2bf(t[tx][ty + i * 8]);
}

// ---------------- RMSNorm (f32 in, bf16 out), one block per row, D=1024
__global__ __launch_bounds__(256) void rmsnorm_kernel(const float* __restrict__ x,
                                                      const float* __restrict__ g,
                                                      u16* __restrict__ out) {
  const int row = blockIdx.x;
  const int t = threadIdx.x;
  const float4 v = ((const float4*)(x + (size_t)row * kD))[t];
  float ss = v.x * v.x + v.y * v.y + v.z * v.z + v.w * v.w;
#pragma unroll
  for (int o = 1; o < 64; o <<= 1) ss += __shfl_xor(ss, o, 64);
  __shared__ float red[4];
  if ((t & 63) == 0) red[t >> 6] = ss;
  __syncthreads();
  const float tot = red[0] + red[1] + red[2] + red[3];
  const float sc = rsqrtf(tot * (1.0f / kD) + kEPS);
  const float4 gv = ((const float4*)g)[t];
  const uint32_t lo = (uint32_t)f2bf(v.x * sc * gv.x) | ((uint32_t)f2bf(v.y * sc * gv.y) << 16);
  const uint32_t hi = (uint32_t)f2bf(v.z * sc * gv.z) | ((uint32_t)f2bf(v.w * sc * gv.w) << 16);
  *(uint2*)(out + (size_t)row * kD + t * 4) = make_uint2(lo, hi);
}

// ---------------- CHAMPION (767 us total): 256x256 lockstep 4-phase GEMM,
// spread staging, vmcnt(2). Byte-identical to the round-4 submission.
// MODE 2: Cf = v*silu(aux) + res
// MODE 4: Cf = v + res
// MODE 5: Cb = bf16(v)
// MODE 7: pair coeffs: v1=z, v2=dt -> Cf = sigm(-v2), C2 = sigm(v1)*sigm(v2), Nout=N/2
template <int MODE>
__global__ __launch_bounds__(512) void gemm256(
    const u16* __restrict__ A, const u16* __restrict__ Bt,
    const float* __restrict__ bias, const float* __restrict__ bias2,
    const u16* __restrict__ aux, int auxld,
    const float* __restrict__ res, float* __restrict__ Cf,
    u16* __restrict__ Cb, float* __restrict__ C2,
    int M, int N, int K) {
  __shared__ u16 sm[65536];  // 128 KiB
  const int tid = threadIdx.x;
  const int lane = tid & 63;
  const int wave = tid >> 6;
  const int wr = wave >> 2, wc = wave & 3;  // 2 x 4 wave grid

  // bijective XCD swizzle (m204)
  const int gx = gridDim.x;
  const int nwg = gx * gridDim.y;
  const int bid = blockIdx.y * gx + blockIdx.x;
  const int q = nwg >> 3, r = nwg & 7;
  const int xcd = bid & 7, idx0 = bid >> 3;
  const int wg = (xcd < r ? xcd * (q + 1) : r * (q + 1) + (xcd - r) * q) + idx0;
  const int m0 = (wg / gx) * 256, n0 = (wg % gx) * 256;

  const int NK = K >> 6;

  const int l8 = lane >> 3, l7 = lane & 7;
  const int rsub = wave * 8 + l8;
  const int kel = (l7 ^ l8) * 8;
  const size_t srcA = (size_t)(m0 + rsub) * K + kel;
  const size_t srcB = (size_t)(n0 + rsub) * K + kel;

  // half: 0 = A rows 0-127, 1 = A rows 128-255, 2 = B rows 0-127, 3 = B rows 128-255
  auto stage_half = [&](int kt, int half) {
    const int bsel = (kt & 1) * 32768;
    if (half < 2) {
      u16* d = sm + bsel + tid * 8 + half * 8192;
      const u16* s = A + srcA + (size_t)kt * 64 + (size_t)(half * 2) * 64 * K;
      gload_lds16(s, d);
      gload_lds16(s + (size_t)64 * K, d + 4096);
    } else {
      const int hh = half - 2;
      u16* d = sm + bsel + 16384 + tid * 8 + hh * 8192;
      const u16* s = Bt + srcB + (size_t)kt * 64 + (size_t)(hh * 2) * 64 * K;
      gload_lds16(s, d);
      gload_lds16(s + (size_t)64 * K, d + 4096);
    }
  };

  const int ra = lane & 15;
  const int kx0 = ((lane >> 4) ^ l7) * 8;
  const int kx1 = (((lane >> 4) + 4) ^ l7) * 8;

  f32x4 acc[8][4] = {};
  bf16x8 al[4][2], ah[4][2], bl[2][2], bh[2][2];

  stage_half(0, 0); stage_half(0, 1); stage_half(0, 2); stage_half(0, 3);
  stage_half(1, 0);
  asm volatile("s_waitcnt vmcnt(2)");
  asm volatile("s_barrier" ::: "memory");

  for (int h = 0; h < NK; ++h) {
    const u16* as = sm + (h & 1) * 32768 + (wr * 128 + ra) * 64;
    const u16* bs = sm + (h & 1) * 32768 + 16384 + (wc * 64 + ra) * 64;

    // ---- Phase 1: read A-lo + B-lo; stage (h+1,#1)
#pragma unroll
    for (int mi = 0; mi < 4; ++mi) {
      al[mi][0] = *(const bf16x8*)(as + mi * 16 * 64 + kx0);
      al[mi][1] = *(const bf16x8*)(as + mi * 16 * 64 + kx1);
    }
#pragma unroll
    for (int ni = 0; ni < 2; ++ni) {
      bl[ni][0] = *(const bf16x8*)(bs + ni * 16 * 64 + kx0);
      bl[ni][1] = *(const bf16x8*)(bs + ni * 16 * 64 + kx1);
    }
    if (h + 1 < NK) stage_half(h + 1, 1);
    asm volatile("s_barrier" ::: "memory");
    asm volatile("s_waitcnt lgkmcnt(0)");
    __builtin_amdgcn_s_setprio(1);
#pragma unroll
    for (int mi = 0; mi < 4; ++mi)
#pragma unroll
      for (int ni = 0; ni < 2; ++ni)
#pragma unroll
        for (int kk = 0; kk < 2; ++kk)
          acc[mi][ni] = __builtin_amdgcn_mfma_f32_16x16x32_bf16(al[mi][kk], bl[ni][kk], acc[mi][ni], 0, 0, 0);
    __builtin_amdgcn_s_setprio(0);
    asm volatile("s_barrier" ::: "memory");

    // ---- Phase 2: read B-hi; stage (h+1,#2)
#pragma unroll
    for (int ni = 0; ni < 2; ++ni) {
      bh[ni][0] = *(const bf16x8*)(bs + (32 + ni * 16) * 64 + kx0);
      bh[ni][1] = *(const bf16x8*)(bs + (32 + ni * 16) * 64 + kx1);
    }
    if (h + 1 < NK) stage_half(h + 1, 2);
    asm volatile("s_barrier" ::: "memory");
    asm volatile("s_waitcnt lgkmcnt(0)");
    __builtin_amdgcn_s_setprio(1);
#pragma unroll
    for (int mi = 0; mi < 4; ++mi)
#pragma unroll
      for (int ni = 0; ni < 2; ++ni)
#pragma unroll
        for (int kk = 0; kk < 2; ++kk)
          acc[mi][2 + ni] = __builtin_amdgcn_mfma_f32_16x16x32_bf16(al[mi][kk], bh[ni][kk], acc[mi][2 + ni], 0, 0, 0);
    __builtin_amdgcn_s_setprio(0);
    asm volatile("s_barrier" ::: "memory");

    // ---- Phase 3: read A-hi; stage (h+1,#3)
#pragma unroll
    for (int mi = 0; mi < 4; ++mi) {
      ah[mi][0] = *(const bf16x8*)(as + (64 + mi * 16) * 64 + kx0);
      ah[mi][1] = *(const bf16x8*)(as + (64 + mi * 16) * 64 + kx1);
    }
    if (h + 1 < NK) stage_half(h + 1, 3);
    asm volatile("s_barrier" ::: "memory");
    asm volatile("s_waitcnt lgkmcnt(0)");
    __builtin_amdgcn_s_setprio(1);
#pragma unroll
    for (int mi = 0; mi < 4; ++mi)
#pragma unroll
      for (int ni = 0; ni < 2; ++ni)
#pragma unroll
        for (int kk = 0; kk < 2; ++kk)
          acc[4 + mi][ni] = __builtin_amdgcn_mfma_f32_16x16x32_bf16(ah[mi][kk], bl[ni][kk], acc[4 + mi][ni], 0, 0, 0);
    __builtin_amdgcn_s_setprio(0);
    asm volatile("s_barrier" ::: "memory");

    // ---- Phase 4: stage (h+2,#0); MFMA hi x hi; counted vmcnt; barrier
    if (h + 2 < NK) stage_half(h + 2, 0);
    asm volatile("s_barrier" ::: "memory");
    __builtin_amdgcn_s_setprio(1);
#pragma unroll
    for (int mi = 0; mi < 4; ++mi)
#pragma unroll
      for (int ni = 0; ni < 2; ++ni)
#pragma unroll
        for (int kk = 0; kk < 2; ++kk)
          acc[4 + mi][2 + ni] = __builtin_amdgcn_mfma_f32_16x16x32_bf16(ah[mi][kk], bh[ni][kk], acc[4 + mi][2 + ni], 0, 0, 0);
    __builtin_amdgcn_s_setprio(0);
    if (h + 2 < NK) asm volatile("s_waitcnt vmcnt(2)");
    else            asm volatile("s_waitcnt vmcnt(0)");
    asm volatile("s_barrier" ::: "memory");
  }

  // ---- epilogue. C/D layout: col = lane&15, row = (lane>>4)*4 + j
  const int ca = ra;
  const int rq = (lane >> 4) * 4;
  if (MODE == 7) {
    const int Nout = N >> 1;
#pragma unroll
    for (int mi = 0; mi < 8; ++mi) {
#pragma unroll
      for (int ni = 0; ni < 2; ++ni) {
        const int cout = (n0 >> 1) + wc * 32 + ni * 16 + ca;
        const float b1 = bias[cout], b2 = bias2[cout];
#pragma unroll
        for (int j = 0; j < 4; ++j) {
          const int rr = m0 + wr * 128 + mi * 16 + rq + j;
          const size_t idx = (size_t)rr * Nout + cout;
          const float v1 = acc[mi][ni][j] + b1;
          const float v2 = acc[mi][2 + ni][j] + b2;
          Cf[idx] = sigm(-v2);              // decay A
          C2[idx] = sigm(v1) * sigm(v2);    // input B
        }
      }
    }
  } else {
#pragma unroll
    for (int mi = 0; mi < 8; ++mi) {
#pragma unroll
      for (int ni = 0; ni < 4; ++ni) {
        const int c = n0 + wc * 64 + ni * 16 + ca;
        const float bz = bias[c];
#pragma unroll
        for (int j = 0; j < 4; ++j) {
          const int rr = m0 + wr * 128 + mi * 16 + rq + j;
          const size_t idx = (size_t)rr * N + c;
          const float v = acc[mi][ni][j] + bz;
          if (MODE == 2) {
            const float a = bf2f(aux[(size_t)rr * auxld + c]);
            Cf[idx] = v * (a * sigm(a)) + res[idx];
          } else if (MODE == 4) {
            Cf[idx] = v + res[idx];
          } else {  // MODE 5
            Cb[idx] = f2bf(v);
          }
        }
      }
    }
  }
}

// ---------------- MODE6 specialist (round-8 kernel, fixed swizzle, 0 conflicts,
// MODE6 measured 299-303 us): 256x128 lockstep 3-phase, BK=32, 8 waves 4Mx2N,
// __launch_bounds__(512,4) -> 2 blocks/CU; supertile raster.
__global__ __launch_bounds__(512, 4) void gemm_ffn(
    const u16* __restrict__ A, const u16* __restrict__ Bt,
    const float* __restrict__ bias, const float* __restrict__ bias2,
    u16* __restrict__ Cb, int M, int N, int K) {
  __shared__ u16 sm[24576];  // 48 KiB
  const int tid = threadIdx.x;
  const int lane = tid & 63;
  const int wave = tid >> 6;
  const int wr = wave >> 1, wc = wave & 1;  // 4M x 2N

  const int gx = gridDim.x;
  const int nwg = gx * gridDim.y;
  const int bid = blockIdx.y * gx + blockIdx.x;
  const int q = nwg >> 3, r = nwg & 7;
  const int xcd = bid & 7, idx0 = bid >> 3;
  const int wg = (xcd < r ? xcd * (q + 1) : r * (q + 1) + (xcd - r) * q) + idx0;
  const int per = gridDim.y * 4;
  const int sg = wg / per, srem = wg % per;
  const int m0 = (srem >> 2) * 256;
  const int n0 = (sg * 4 + (srem & 3)) * 128;

  const int NK = K >> 5;

  const int rsub = wave * 16 + (lane >> 2);
  const int kel = ((lane & 3) ^ ((lane >> 3) & 3)) * 8;
  const size_t srcA = (size_t)(m0 + rsub) * K + kel;
  const size_t srcB = (size_t)(n0 + rsub) * K + kel;

  auto stageA = [&](int kt) {
    u16* d = sm + (kt & 1) * 12288 + tid * 8;
    const u16* s = A + srcA + (size_t)kt * 32;
    gload_lds16(s, d);
    gload_lds16(s + (size_t)128 * K, d + 4096);
  };
  auto stageB = [&](int kt) {
    gload_lds16(Bt + srcB + (size_t)kt * 32,
                sm + (kt & 1) * 12288 + 8192 + tid * 8);
  };

  const int ra = lane & 15;
  const int rb = ra * 32 + ((((lane >> 4) ^ (ra >> 1)) & 3) << 3);

  f32x4 acc[4][4] = {};
  bf16x8 af[4], bfr[4];

  stageA(0); stageB(0);
  if (NK > 1) { stageA(1); stageB(1); }
  asm volatile("s_waitcnt vmcnt(3)");
  asm volatile("s_barrier" ::: "memory");

  for (int h = 0; h < NK; ++h) {
    const u16* Az = sm + (h & 1) * 12288 + wr * 2048;
    const u16* Bz = sm + (h & 1) * 12288 + 8192 + wc * 2048;

#pragma unroll
    for (int mi = 0; mi < 4; ++mi) af[mi] = *(const bf16x8*)(Az + mi * 512 + rb);
    bfr[0] = *(const bf16x8*)(Bz + rb);
    bfr[1] = *(const bf16x8*)(Bz + 512 + rb);
    asm volatile("s_barrier" ::: "memory");
    asm volatile("s_waitcnt lgkmcnt(0)");
    __builtin_amdgcn_s_setprio(1);
#pragma unroll
    for (int mi = 0; mi < 4; ++mi)
#pragma unroll
      for (int ni = 0; ni < 2; ++ni)
        acc[mi][ni] = __builtin_amdgcn_mfma_f32_16x16x32_bf16(af[mi], bfr[ni], acc[mi][ni], 0, 0, 0);
    __builtin_amdgcn_s_setprio(0);
    asm volatile("s_barrier" ::: "memory");

    bfr[2] = *(const bf16x8*)(Bz + 1024 + rb);
    bfr[3] = *(const bf16x8*)(Bz + 1536 + rb);
    if (h + 2 < NK) stageA(h + 2);
    asm volatile("s_barrier" ::: "memory");
    asm volatile("s_waitcnt lgkmcnt(0)");
    __builtin_amdgcn_s_setprio(1);
#pragma unroll
    for (int mi = 0; mi < 4; ++mi)
      acc[mi][2] = __builtin_amdgcn_mfma_f32_16x16x32_bf16(af[mi], bfr[2], acc[mi][2], 0, 0, 0);
    __builtin_amdgcn_s_setprio(0);
    asm volatile("s_barrier" ::: "memory");

    if (h + 2 < NK) stageB(h + 2);
    __builtin_amdgcn_s_setprio(1);
#pragma unroll
    for (int mi = 0; mi < 4; ++mi)
      acc[mi][3] = __builtin_amdgcn_mfma_f32_16x16x32_bf16(af[mi], bfr[3], acc[mi][3], 0, 0, 0);
    __builtin_amdgcn_s_setprio(0);
    if (h + 2 < NK) asm volatile("s_waitcnt vmcnt(3)");
    else            asm volatile("s_waitcnt vmcnt(0)");
    asm volatile("s_barrier" ::: "memory");
  }

  // pair epilogue: v1=fca(gate), v2=fc -> Cb = bf16(v2*silu(v1)), Nout=N/2
  const int ca = lane & 15;
  const int rq = (lane >> 4) * 4;
  const int Nout = N >> 1;
#pragma unroll
  for (int mi = 0; mi < 4; ++mi) {
#pragma unroll
    for (int ni = 0; ni < 2; ++ni) {
      const int cout = (n0 >> 1) + wc * 32 + ni * 16 + ca;
      const float b1 = bias[cout], b2 = bias2[cout];
#pragma unroll
      for (int j = 0; j < 4; ++j) {
        const int rr = m0 + wr * 64 + mi * 16 + rq + j;
        const size_t idx = (size_t)rr * Nout + cout;
        const float v1 = acc[mi][ni][j] + b1;
        const float v2 = acc[mi][2 + ni][j] + b2;
        Cb[idx] = f2bf(v2 * (v1 * sigm(v1)));
      }
    }
  }
}

// ---------------- chunked scan: h[l] = A[l]*h[l-1] + B[l]
__global__ __launch_bounds__(256) void scan_phase1(const float* __restrict__ Aa,
                                                   const float* __restrict__ Bv,
                                                   float* __restrict__ P,
                                                   float* __restrict__ S) {
  const int d = blockIdx.x * 256 + threadIdx.x;
  const int c = blockIdx.y, b = blockIdx.z;
  size_t base = ((size_t)b * kL + (size_t)c * kLC) * kD + d;
  float p = 1.0f, s = 0.0f;
#pragma unroll 4
  for (int l = 0; l < kLC; ++l) {
    const float a = Aa[base];
    const float bv = Bv[base];
    p *= a;
    s = fmaf(a, s, bv);
    base += kD;
  }
  const size_t o = ((size_t)b * kNC + c) * kD + d;
  P[o] = p; S[o] = s;
}

__global__ __launch_bounds__(256) void scan_phase2(const float* __restrict__ P,
                                                   const float* __restrict__ S,
                                                   const float* __restrict__ hidden,
                                                   float* __restrict__ Hini) {
  const int d = blockIdx.x * 256 + threadIdx.x;
  const int b = blockIdx.y;
  float carry = hidden[(size_t)b * kD + d];
  for (int c = 0; c < kNC; ++c) {
    const size_t o = ((size_t)b * kNC + c) * kD + d;
    Hini[o] = carry;
    carry = fmaf(P[o], carry, S[o]);
  }
}

__global__ __launch_bounds__(256) void scan_phase3(const float* __restrict__ Aa,
                                                   const float* __restrict__ Bv,
                                                   const float* __restrict__ Hini,
                                                   float* __restrict__ Hout,
                                                   u16* __restrict__ Hbf) {
  const int d = blockIdx.x * 256 + threadIdx.x;
  const int c = blockIdx.y, b = blockIdx.z;
  float h = Hini[((size_t)b * kNC + c) * kD + d];
  size_t base = ((size_t)b * kL + (size_t)c * kLC) * kD + d;
#pragma unroll 4
  for (int l = 0; l < kLC; ++l) {
    h = fmaf(Aa[base], h, Bv[base]);
    Hout[base] = h;
    Hbf[base] = f2bf(h);
    base += kD;
  }
}

// ---------------- host
extern "C" void kernel_launch(void* const* d_in, const int* in_sizes, int n_in,
                              void* d_out, int out_size, void* d_ws, size_t ws_size,
                              hipStream_t stream) {
  const float* x      = (const float*)d_in[0];
  const float* hidden = (const float*)d_in[1];
  const float* w_ln_z = (const float*)d_in[2];
  const float* b_ln_z = (const float*)d_in[3];
  const float* w_dt   = (const float*)d_in[4];
  const float* b_dt   = (const float*)d_in[5];
  const float* w_y    = (const float*)d_in[6];
  const float* b_y    = (const float*)d_in[7];
  const float* w_yact = (const float*)d_in[8];
  const float* b_yact = (const float*)d_in[9];
  const float* w_fc   = (const float*)d_in[10];
  const float* b_fc   = (const float*)d_in[11];
  const float* w_fca  = (const float*)d_in[12];
  const float* b_fca  = (const float*)d_in[13];
  const float* w_out  = (const float*)d_in[14];
  const float* b_out  = (const float*)d_in[15];
  const float* g_sio  = (const float*)d_in[16];
  const float* g_ffn  = (const float*)d_in[17];

  char* ws = (char*)d_ws;
  const size_t MiB = 1ull << 20;
  u16* wzdT  = (u16*)(ws + 0 * MiB);      // [2048,1024] paired z|dt, 4 MiB
  u16* wyaT  = (u16*)(ws + 4 * MiB);      // 2 MiB
  u16* wyT   = (u16*)(ws + 6 * MiB);      // 2 MiB
  u16* wfgT  = (u16*)(ws + 8 * MiB);      // [8192,1024] paired fca|fc, 16 MiB
  u16* woutT = (u16*)(ws + 24 * MiB);     // [1024,4096] 8 MiB
  u16*   xn    = (u16*)(ws + 33 * MiB);   // [M,D] bf16 32 MiB (reused as xn2)
  u16*   yabuf = (u16*)(ws + 65 * MiB);   // [M,D] bf16 32 MiB
  float* Abuf  = (float*)(ws + 97 * MiB); // [M,D] f32 64 MiB (reused as x1)
  float* Bvbuf = (float*)(ws + 161 * MiB);// [M,D] f32 64 MiB (dead after scan)
  u16*   hbf   = (u16*)(ws + 225 * MiB);  // [M,D] bf16 32 MiB (dead after y-GEMM)
  u16*   Ubuf  = (u16*)(ws + 161 * MiB);  // [M,FF] bf16 128 MiB, overlays dead Bv/hbf
  float* Pbuf  = (float*)(ws + 289 * MiB);
  float* Sbuf  = (float*)(ws + 290 * MiB);
  float* Hini  = (float*)(ws + 291 * MiB);// ends 292 MiB

  float* xout = (float*)d_out;
  float* hout = xout + (size_t)kM * kD;
  float* x1 = Abuf;

  // merged weight transpose: 2048+8192+1024+1024+4096 = 16384 blocks
  wtrans_all<<<16384, dim3(32, 8), 0, stream>>>(
      w_ln_z, w_dt, w_fca, w_fc, w_yact, w_y, w_out,
      wzdT, wfgT, wyaT, wyT, woutT);

  rmsnorm_kernel<<<kM, 256, 0, stream>>>(x, g_sio, xn);

  // paired z|dt GEMM -> A = sigm(-dt), Bv = sigm(z)*sigm(dt)
  gemm256<7><<<dim3(2048 / 256, kM / 256), 512, 0, stream>>>(
      xn, wzdT, b_ln_z, b_dt, nullptr, 0, nullptr, Abuf, nullptr, Bvbuf, kM, 2048, kD);
  // ya = xn @ w_y_act + b (bf16)
  gemm256<5><<<dim3(kD / 256, kM / 256), 512, 0, stream>>>(
      xn, wyaT, b_yact, nullptr, nullptr, 0, nullptr, nullptr, yabuf, nullptr, kM, kD, kD);

  scan_phase1<<<dim3(kD / 256, kNC, kB), 256, 0, stream>>>(Abuf, Bvbuf, Pbuf, Sbuf);
  scan_phase2<<<dim3(kD / 256, kB), 256, 0, stream>>>(Pbuf, Sbuf, hidden, Hini);
  scan_phase3<<<dim3(kD / 256, kNC, kB), 256, 0, stream>>>(Abuf, Bvbuf, Hini, hout, hbf);

  // x1 = (h @ w_y + b_y) * silu(ya) + x   (x1 reuses Abuf)
  gemm256<2><<<dim3(kD / 256, kM / 256), 512, 0, stream>>>(
      hbf, wyT, b_y, nullptr, yabuf, kD, x, x1, nullptr, nullptr, kM, kD, kD);

  rmsnorm_kernel<<<kM, 256, 0, stream>>>(x1, g_ffn, xn);

  // paired FFN up+gate: U = fc * silu(fca) — MODE6 specialist kernel
  gemm_ffn<<<dim3(8192 / 128, kM / 256), 512, 0, stream>>>(
      xn, wfgT, b_fca, b_fc, Ubuf, kM, 8192, kD);

  // xout = U @ w_out + b_out + x1  (K=4096)
  gemm256<4><<<dim3(kD / 256, kM / 256), 512, 0, stream>>>(
      Ubuf, woutT, b_out, nullptr, nullptr, 0, x1, xout, nullptr, nullptr, kM, kD, kFF);
}

// Round 13
// 732.463 us; speedup vs baseline: 1.1117x; 1.0364x over previous
//
#include <hip/hip_runtime.h>
#include <stdint.h>

using u16 = unsigned short;
typedef __attribute__((ext_vector_type(8))) __bf16 bf16x8;
typedef __attribute__((ext_vector_type(4))) float f32x4;

#define DEV __device__ __forceinline__

static constexpr int kB = 4, kL = 4096, kD = 1024, kFF = 4096;
static constexpr int kM = kB * kL;
static constexpr int kLC = 256, kNC = kL / kLC;
static constexpr float kEPS = 1e-6f;

DEV u16 f2bf(float v) {
  union { float f; uint32_t u; } x; x.f = v;
  uint32_t r = x.u + 0x7FFFu + ((x.u >> 16) & 1u);  // RNE
  return (u16)(r >> 16);
}
DEV float bf2f(u16 u) {
  union { uint32_t u; float f; } x; x.u = (uint32_t)u << 16; return x.f;
}
DEV float sigm(float x) { return 1.0f / (1.0f + __expf(-x)); }

DEV void gload_lds16(const void* g, void* l) {
  __builtin_amdgcn_global_load_lds(
      (const __attribute__((address_space(1))) void*)g,
      (__attribute__((address_space(3))) void*)l, 16, 0, 0);
}

// ---------------- merged weight transpose + f32->bf16 (all 5 weights, 1 launch)
__global__ __launch_bounds__(256) void wtrans_all(
    const float* __restrict__ w_ln_z, const float* __restrict__ w_dt,
    const float* __restrict__ w_fca, const float* __restrict__ w_fc,
    const float* __restrict__ w_yact, const float* __restrict__ w_y,
    const float* __restrict__ w_out_,
    u16* __restrict__ wzdT, u16* __restrict__ wfgT, u16* __restrict__ wyaT,
    u16* __restrict__ wyT, u16* __restrict__ woutT) {
  const int bid = blockIdx.x;
  const float *a, *b; u16* out; int K, Ncols, bx, local; bool pair;
  if (bid < 2048)       { local = bid;         a = w_ln_z; b = w_dt; out = wzdT;  K = 1024; Ncols = 1024; bx = 64;  pair = true;  }
  else if (bid < 10240) { local = bid - 2048;  a = w_fca;  b = w_fc; out = wfgT;  K = 1024; Ncols = 4096; bx = 256; pair = true;  }
  else if (bid < 11264) { local = bid - 10240; a = w_yact; b = nullptr; out = wyaT; K = 1024; Ncols = 1024; bx = 32; pair = false; }
  else if (bid < 12288) { local = bid - 11264; a = w_y;    b = nullptr; out = wyT;  K = 1024; Ncols = 1024; bx = 32; pair = false; }
  else                  { local = bid - 12288; a = w_out_; b = nullptr; out = woutT; K = 4096; Ncols = 1024; bx = 32; pair = false; }
  const int n0 = (local % bx) * 32, k0 = (local / bx) * 32;
  __shared__ float t[32][33];
  const int tx = threadIdx.x, ty = threadIdx.y;
  const float* src; int c0;
  if (pair) { src = ((n0 >> 5) & 1) ? b : a; c0 = (n0 >> 6) * 32; }
  else      { src = a; c0 = n0; }
#pragma unroll
  for (int i = 0; i < 4; ++i)
    t[ty + i * 8][tx] = src[(size_t)(k0 + ty + i * 8) * Ncols + (c0 + tx)];
  __syncthreads();
#pragma unroll
  for (int i = 0; i < 4; ++i)
    out[(size_t)(n0 + ty + i * 8) * K + (k0 + tx)] = f2bf(t[tx][ty + i * 8]);
}

// ---------------- RMSNorm (f32 in, bf16 out), one block per row, D=1024
__global__ __launch_bounds__(256) void rmsnorm_kernel(const float* __restrict__ x,
                                                      const float* __restrict__ g,
                                                      u16* __restrict__ out) {
  const int row = blockIdx.x;
  const int t = threadIdx.x;
  const float4 v = ((const float4*)(x + (size_t)row * kD))[t];
  float ss = v.x * v.x + v.y * v.y + v.z * v.z + v.w * v.w;
#pragma unroll
  for (int o = 1; o < 64; o <<= 1) ss += __shfl_xor(ss, o, 64);
  __shared__ float red[4];
  if ((t & 63) == 0) red[t >> 6] = ss;
  __syncthreads();
  const float tot = red[0] + red[1] + red[2] + red[3];
  const float sc = rsqrtf(tot * (1.0f / kD) + kEPS);
  const float4 gv = ((const float4*)g)[t];
  const uint32_t lo = (uint32_t)f2bf(v.x * sc * gv.x) | ((uint32_t)f2bf(v.y * sc * gv.y) << 16);
  const uint32_t hi = (uint32_t)f2bf(v.z * sc * gv.z) | ((uint32_t)f2bf(v.w * sc * gv.w) << 16);
  *(uint2*)(out + (size_t)row * kD + t * 4) = make_uint2(lo, hi);
}

// ---------------- CHAMPION: 256x256 lockstep 4-phase GEMM, spread staging,
// vmcnt(2). Identical to round-12. MODE7's C2 (Bv) now written bf16.
// MODE 2: Cf = v*silu(aux) + res
// MODE 4: Cf = v + res
// MODE 5: Cb = bf16(v)
// MODE 7: pair coeffs: v1=z, v2=dt -> Cf = sigm(-v2) [f32], C2b = bf16(sigm(v1)*sigm(v2))
template <int MODE>
__global__ __launch_bounds__(512) void gemm256(
    const u16* __restrict__ A, const u16* __restrict__ Bt,
    const float* __restrict__ bias, const float* __restrict__ bias2,
    const u16* __restrict__ aux, int auxld,
    const float* __restrict__ res, float* __restrict__ Cf,
    u16* __restrict__ Cb, u16* __restrict__ C2b,
    int M, int N, int K) {
  __shared__ u16 sm[65536];  // 128 KiB
  const int tid = threadIdx.x;
  const int lane = tid & 63;
  const int wave = tid >> 6;
  const int wr = wave >> 2, wc = wave & 3;  // 2 x 4 wave grid

  // bijective XCD swizzle (m204)
  const int gx = gridDim.x;
  const int nwg = gx * gridDim.y;
  const int bid = blockIdx.y * gx + blockIdx.x;
  const int q = nwg >> 3, r = nwg & 7;
  const int xcd = bid & 7, idx0 = bid >> 3;
  const int wg = (xcd < r ? xcd * (q + 1) : r * (q + 1) + (xcd - r) * q) + idx0;
  const int m0 = (wg / gx) * 256, n0 = (wg % gx) * 256;

  const int NK = K >> 6;

  const int l8 = lane >> 3, l7 = lane & 7;
  const int rsub = wave * 8 + l8;
  const int kel = (l7 ^ l8) * 8;
  const size_t srcA = (size_t)(m0 + rsub) * K + kel;
  const size_t srcB = (size_t)(n0 + rsub) * K + kel;

  auto stage_half = [&](int kt, int half) {
    const int bsel = (kt & 1) * 32768;
    if (half < 2) {
      u16* d = sm + bsel + tid * 8 + half * 8192;
      const u16* s = A + srcA + (size_t)kt * 64 + (size_t)(half * 2) * 64 * K;
      gload_lds16(s, d);
      gload_lds16(s + (size_t)64 * K, d + 4096);
    } else {
      const int hh = half - 2;
      u16* d = sm + bsel + 16384 + tid * 8 + hh * 8192;
      const u16* s = Bt + srcB + (size_t)kt * 64 + (size_t)(hh * 2) * 64 * K;
      gload_lds16(s, d);
      gload_lds16(s + (size_t)64 * K, d + 4096);
    }
  };

  const int ra = lane & 15;
  const int kx0 = ((lane >> 4) ^ l7) * 8;
  const int kx1 = (((lane >> 4) + 4) ^ l7) * 8;

  f32x4 acc[8][4] = {};
  bf16x8 al[4][2], ah[4][2], bl[2][2], bh[2][2];

  stage_half(0, 0); stage_half(0, 1); stage_half(0, 2); stage_half(0, 3);
  stage_half(1, 0);
  asm volatile("s_waitcnt vmcnt(2)");
  asm volatile("s_barrier" ::: "memory");

  for (int h = 0; h < NK; ++h) {
    const u16* as = sm + (h & 1) * 32768 + (wr * 128 + ra) * 64;
    const u16* bs = sm + (h & 1) * 32768 + 16384 + (wc * 64 + ra) * 64;

    // ---- Phase 1: read A-lo + B-lo; stage (h+1,#1)
#pragma unroll
    for (int mi = 0; mi < 4; ++mi) {
      al[mi][0] = *(const bf16x8*)(as + mi * 16 * 64 + kx0);
      al[mi][1] = *(const bf16x8*)(as + mi * 16 * 64 + kx1);
    }
#pragma unroll
    for (int ni = 0; ni < 2; ++ni) {
      bl[ni][0] = *(const bf16x8*)(bs + ni * 16 * 64 + kx0);
      bl[ni][1] = *(const bf16x8*)(bs + ni * 16 * 64 + kx1);
    }
    if (h + 1 < NK) stage_half(h + 1, 1);
    asm volatile("s_barrier" ::: "memory");
    asm volatile("s_waitcnt lgkmcnt(0)");
    __builtin_amdgcn_s_setprio(1);
#pragma unroll
    for (int mi = 0; mi < 4; ++mi)
#pragma unroll
      for (int ni = 0; ni < 2; ++ni)
#pragma unroll
        for (int kk = 0; kk < 2; ++kk)
          acc[mi][ni] = __builtin_amdgcn_mfma_f32_16x16x32_bf16(al[mi][kk], bl[ni][kk], acc[mi][ni], 0, 0, 0);
    __builtin_amdgcn_s_setprio(0);
    asm volatile("s_barrier" ::: "memory");

    // ---- Phase 2: read B-hi; stage (h+1,#2)
#pragma unroll
    for (int ni = 0; ni < 2; ++ni) {
      bh[ni][0] = *(const bf16x8*)(bs + (32 + ni * 16) * 64 + kx0);
      bh[ni][1] = *(const bf16x8*)(bs + (32 + ni * 16) * 64 + kx1);
    }
    if (h + 1 < NK) stage_half(h + 1, 2);
    asm volatile("s_barrier" ::: "memory");
    asm volatile("s_waitcnt lgkmcnt(0)");
    __builtin_amdgcn_s_setprio(1);
#pragma unroll
    for (int mi = 0; mi < 4; ++mi)
#pragma unroll
      for (int ni = 0; ni < 2; ++ni)
#pragma unroll
        for (int kk = 0; kk < 2; ++kk)
          acc[mi][2 + ni] = __builtin_amdgcn_mfma_f32_16x16x32_bf16(al[mi][kk], bh[ni][kk], acc[mi][2 + ni], 0, 0, 0);
    __builtin_amdgcn_s_setprio(0);
    asm volatile("s_barrier" ::: "memory");

    // ---- Phase 3: read A-hi; stage (h+1,#3)
#pragma unroll
    for (int mi = 0; mi < 4; ++mi) {
      ah[mi][0] = *(const bf16x8*)(as + (64 + mi * 16) * 64 + kx0);
      ah[mi][1] = *(const bf16x8*)(as + (64 + mi * 16) * 64 + kx1);
    }
    if (h + 1 < NK) stage_half(h + 1, 3);
    asm volatile("s_barrier" ::: "memory");
    asm volatile("s_waitcnt lgkmcnt(0)");
    __builtin_amdgcn_s_setprio(1);
#pragma unroll
    for (int mi = 0; mi < 4; ++mi)
#pragma unroll
      for (int ni = 0; ni < 2; ++ni)
#pragma unroll
        for (int kk = 0; kk < 2; ++kk)
          acc[4 + mi][ni] = __builtin_amdgcn_mfma_f32_16x16x32_bf16(ah[mi][kk], bl[ni][kk], acc[4 + mi][ni], 0, 0, 0);
    __builtin_amdgcn_s_setprio(0);
    asm volatile("s_barrier" ::: "memory");

    // ---- Phase 4: stage (h+2,#0); MFMA hi x hi; counted vmcnt; barrier
    if (h + 2 < NK) stage_half(h + 2, 0);
    asm volatile("s_barrier" ::: "memory");
    __builtin_amdgcn_s_setprio(1);
#pragma unroll
    for (int mi = 0; mi < 4; ++mi)
#pragma unroll
      for (int ni = 0; ni < 2; ++ni)
#pragma unroll
        for (int kk = 0; kk < 2; ++kk)
          acc[4 + mi][2 + ni] = __builtin_amdgcn_mfma_f32_16x16x32_bf16(ah[mi][kk], bh[ni][kk], acc[4 + mi][2 + ni], 0, 0, 0);
    __builtin_amdgcn_s_setprio(0);
    if (h + 2 < NK) asm volatile("s_waitcnt vmcnt(2)");
    else            asm volatile("s_waitcnt vmcnt(0)");
    asm volatile("s_barrier" ::: "memory");
  }

  // ---- epilogue. C/D layout: col = lane&15, row = (lane>>4)*4 + j
  const int ca = ra;
  const int rq = (lane >> 4) * 4;
  if (MODE == 7) {
    const int Nout = N >> 1;
#pragma unroll
    for (int mi = 0; mi < 8; ++mi) {
#pragma unroll
      for (int ni = 0; ni < 2; ++ni) {
        const int cout = (n0 >> 1) + wc * 32 + ni * 16 + ca;
        const float b1 = bias[cout], b2 = bias2[cout];
#pragma unroll
        for (int j = 0; j < 4; ++j) {
          const int rr = m0 + wr * 128 + mi * 16 + rq + j;
          const size_t idx = (size_t)rr * Nout + cout;
          const float v1 = acc[mi][ni][j] + b1;
          const float v2 = acc[mi][2 + ni][j] + b2;
          Cf[idx] = sigm(-v2);                       // decay A (f32: chunk products need precision)
          C2b[idx] = f2bf(sigm(v1) * sigm(v2));      // input B (bf16: <=0.2% rel, additive only)
        }
      }
    }
  } else {
#pragma unroll
    for (int mi = 0; mi < 8; ++mi) {
#pragma unroll
      for (int ni = 0; ni < 4; ++ni) {
        const int c = n0 + wc * 64 + ni * 16 + ca;
        const float bz = bias[c];
#pragma unroll
        for (int j = 0; j < 4; ++j) {
          const int rr = m0 + wr * 128 + mi * 16 + rq + j;
          const size_t idx = (size_t)rr * N + c;
          const float v = acc[mi][ni][j] + bz;
          if (MODE == 2) {
            const float a = bf2f(aux[(size_t)rr * auxld + c]);
            Cf[idx] = v * (a * sigm(a)) + res[idx];
          } else if (MODE == 4) {
            Cf[idx] = v + res[idx];
          } else {  // MODE 5
            Cb[idx] = f2bf(v);
          }
        }
      }
    }
  }
}

// ---------------- MODE6 specialist (256x128, 2 blocks/CU, 0 conflicts)
__global__ __launch_bounds__(512, 4) void gemm_ffn(
    const u16* __restrict__ A, const u16* __restrict__ Bt,
    const float* __restrict__ bias, const float* __restrict__ bias2,
    u16* __restrict__ Cb, int M, int N, int K) {
  __shared__ u16 sm[24576];  // 48 KiB
  const int tid = threadIdx.x;
  const int lane = tid & 63;
  const int wave = tid >> 6;
  const int wr = wave >> 1, wc = wave & 1;  // 4M x 2N

  const int gx = gridDim.x;
  const int nwg = gx * gridDim.y;
  const int bid = blockIdx.y * gx + blockIdx.x;
  const int q = nwg >> 3, r = nwg & 7;
  const int xcd = bid & 7, idx0 = bid >> 3;
  const int wg = (xcd < r ? xcd * (q + 1) : r * (q + 1) + (xcd - r) * q) + idx0;
  const int per = gridDim.y * 4;
  const int sg = wg / per, srem = wg % per;
  const int m0 = (srem >> 2) * 256;
  const int n0 = (sg * 4 + (srem & 3)) * 128;

  const int NK = K >> 5;

  const int rsub = wave * 16 + (lane >> 2);
  const int kel = ((lane & 3) ^ ((lane >> 3) & 3)) * 8;
  const size_t srcA = (size_t)(m0 + rsub) * K + kel;
  const size_t srcB = (size_t)(n0 + rsub) * K + kel;

  auto stageA = [&](int kt) {
    u16* d = sm + (kt & 1) * 12288 + tid * 8;
    const u16* s = A + srcA + (size_t)kt * 32;
    gload_lds16(s, d);
    gload_lds16(s + (size_t)128 * K, d + 4096);
  };
  auto stageB = [&](int kt) {
    gload_lds16(Bt + srcB + (size_t)kt * 32,
                sm + (kt & 1) * 12288 + 8192 + tid * 8);
  };

  const int ra = lane & 15;
  const int rb = ra * 32 + ((((lane >> 4) ^ (ra >> 1)) & 3) << 3);

  f32x4 acc[4][4] = {};
  bf16x8 af[4], bfr[4];

  stageA(0); stageB(0);
  if (NK > 1) { stageA(1); stageB(1); }
  asm volatile("s_waitcnt vmcnt(3)");
  asm volatile("s_barrier" ::: "memory");

  for (int h = 0; h < NK; ++h) {
    const u16* Az = sm + (h & 1) * 12288 + wr * 2048;
    const u16* Bz = sm + (h & 1) * 12288 + 8192 + wc * 2048;

#pragma unroll
    for (int mi = 0; mi < 4; ++mi) af[mi] = *(const bf16x8*)(Az + mi * 512 + rb);
    bfr[0] = *(const bf16x8*)(Bz + rb);
    bfr[1] = *(const bf16x8*)(Bz + 512 + rb);
    asm volatile("s_barrier" ::: "memory");
    asm volatile("s_waitcnt lgkmcnt(0)");
    __builtin_amdgcn_s_setprio(1);
#pragma unroll
    for (int mi = 0; mi < 4; ++mi)
#pragma unroll
      for (int ni = 0; ni < 2; ++ni)
        acc[mi][ni] = __builtin_amdgcn_mfma_f32_16x16x32_bf16(af[mi], bfr[ni], acc[mi][ni], 0, 0, 0);
    __builtin_amdgcn_s_setprio(0);
    asm volatile("s_barrier" ::: "memory");

    bfr[2] = *(const bf16x8*)(Bz + 1024 + rb);
    bfr[3] = *(const bf16x8*)(Bz + 1536 + rb);
    if (h + 2 < NK) stageA(h + 2);
    asm volatile("s_barrier" ::: "memory");
    asm volatile("s_waitcnt lgkmcnt(0)");
    __builtin_amdgcn_s_setprio(1);
#pragma unroll
    for (int mi = 0; mi < 4; ++mi)
      acc[mi][2] = __builtin_amdgcn_mfma_f32_16x16x32_bf16(af[mi], bfr[2], acc[mi][2], 0, 0, 0);
    __builtin_amdgcn_s_setprio(0);
    asm volatile("s_barrier" ::: "memory");

    if (h + 2 < NK) stageB(h + 2);
    __builtin_amdgcn_s_setprio(1);
#pragma unroll
    for (int mi = 0; mi < 4; ++mi)
      acc[mi][3] = __builtin_amdgcn_mfma_f32_16x16x32_bf16(af[mi], bfr[3], acc[mi][3], 0, 0, 0);
    __builtin_amdgcn_s_setprio(0);
    if (h + 2 < NK) asm volatile("s_waitcnt vmcnt(3)");
    else            asm volatile("s_waitcnt vmcnt(0)");
    asm volatile("s_barrier" ::: "memory");
  }

  // pair epilogue: v1=fca(gate), v2=fc -> Cb = bf16(v2*silu(v1)), Nout=N/2
  const int ca = lane & 15;
  const int rq = (lane >> 4) * 4;
  const int Nout = N >> 1;
#pragma unroll
  for (int mi = 0; mi < 4; ++mi) {
#pragma unroll
    for (int ni = 0; ni < 2; ++ni) {
      const int cout = (n0 >> 1) + wc * 32 + ni * 16 + ca;
      const float b1 = bias[cout], b2 = bias2[cout];
#pragma unroll
      for (int j = 0; j < 4; ++j) {
        const int rr = m0 + wr * 64 + mi * 16 + rq + j;
        const size_t idx = (size_t)rr * Nout + cout;
        const float v1 = acc[mi][ni][j] + b1;
        const float v2 = acc[mi][2 + ni][j] + b2;
        Cb[idx] = f2bf(v2 * (v1 * sigm(v1)));
      }
    }
  }
}

// ---------------- chunked scan: h[l] = A[l]*h[l-1] + B[l]  (Bv now bf16)
__global__ __launch_bounds__(256) void scan_phase1(const float* __restrict__ Aa,
                                                   const u16* __restrict__ Bv,
                                                   float* __restrict__ P,
                                                   float* __restrict__ S) {
  const int d = blockIdx.x * 256 + threadIdx.x;
  const int c = blockIdx.y, b = blockIdx.z;
  size_t base = ((size_t)b * kL + (size_t)c * kLC) * kD + d;
  float p = 1.0f, s = 0.0f;
#pragma unroll 4
  for (int l = 0; l < kLC; ++l) {
    const float a = Aa[base];
    const float bv = bf2f(Bv[base]);
    p *= a;
    s = fmaf(a, s, bv);
    base += kD;
  }
  const size_t o = ((size_t)b * kNC + c) * kD + d;
  P[o] = p; S[o] = s;
}

__global__ __launch_bounds__(256) void scan_phase2(const float* __restrict__ P,
                                                   const float* __restrict__ S,
                                                   const float* __restrict__ hidden,
                                                   float* __restrict__ Hini) {
  const int d = blockIdx.x * 256 + threadIdx.x;
  const int b = blockIdx.y;
  float carry = hidden[(size_t)b * kD + d];
  for (int c = 0; c < kNC; ++c) {
    const size_t o = ((size_t)b * kNC + c) * kD + d;
    Hini[o] = carry;
    carry = fmaf(P[o], carry, S[o]);
  }
}

__global__ __launch_bounds__(256) void scan_phase3(const float* __restrict__ Aa,
                                                   const u16* __restrict__ Bv,
                                                   const float* __restrict__ Hini,
                                                   float* __restrict__ Hout,
                                                   u16* __restrict__ Hbf) {
  const int d = blockIdx.x * 256 + threadIdx.x;
  const int c = blockIdx.y, b = blockIdx.z;
  float h = Hini[((size_t)b * kNC + c) * kD + d];
  size_t base = ((size_t)b * kL + (size_t)c * kLC) * kD + d;
#pragma unroll 4
  for (int l = 0; l < kLC; ++l) {
    h = fmaf(Aa[base], h, bf2f(Bv[base]));
    Hout[base] = h;
    Hbf[base] = f2bf(h);
    base += kD;
  }
}

// ---------------- host
extern "C" void kernel_launch(void* const* d_in, const int* in_sizes, int n_in,
                              void* d_out, int out_size, void* d_ws, size_t ws_size,
                              hipStream_t stream) {
  const float* x      = (const float*)d_in[0];
  const float* hidden = (const float*)d_in[1];
  const float* w_ln_z = (const float*)d_in[2];
  const float* b_ln_z = (const float*)d_in[3];
  const float* w_dt   = (const float*)d_in[4];
  const float* b_dt   = (const float*)d_in[5];
  const float* w_y    = (const float*)d_in[6];
  const float* b_y    = (const float*)d_in[7];
  const float* w_yact = (const float*)d_in[8];
  const float* b_yact = (const float*)d_in[9];
  const float* w_fc   = (const float*)d_in[10];
  const float* b_fc   = (const float*)d_in[11];
  const float* w_fca  = (const float*)d_in[12];
  const float* b_fca  = (const float*)d_in[13];
  const float* w_out  = (const float*)d_in[14];
  const float* b_out  = (const float*)d_in[15];
  const float* g_sio  = (const float*)d_in[16];
  const float* g_ffn  = (const float*)d_in[17];

  char* ws = (char*)d_ws;
  const size_t MiB = 1ull << 20;
  u16* wzdT  = (u16*)(ws + 0 * MiB);      // [2048,1024] paired z|dt, 4 MiB
  u16* wyaT  = (u16*)(ws + 4 * MiB);      // 2 MiB
  u16* wyT   = (u16*)(ws + 6 * MiB);      // 2 MiB
  u16* wfgT  = (u16*)(ws + 8 * MiB);      // [8192,1024] paired fca|fc, 16 MiB
  u16* woutT = (u16*)(ws + 24 * MiB);     // [1024,4096] 8 MiB
  u16*   xn    = (u16*)(ws + 33 * MiB);   // [M,D] bf16 32 MiB (reused as xn2)
  u16*   yabuf = (u16*)(ws + 65 * MiB);   // [M,D] bf16 32 MiB
  float* Abuf  = (float*)(ws + 97 * MiB); // [M,D] f32 64 MiB (reused as x1)
  u16*   Bvbuf = (u16*)(ws + 161 * MiB);  // [M,D] bf16 32 MiB (dead after scan)
  u16*   hbf   = (u16*)(ws + 225 * MiB);  // [M,D] bf16 32 MiB (dead after y-GEMM)
  u16*   Ubuf  = (u16*)(ws + 161 * MiB);  // [M,FF] bf16 128 MiB, overlays dead Bv/hbf
  float* Pbuf  = (float*)(ws + 289 * MiB);
  float* Sbuf  = (float*)(ws + 290 * MiB);
  float* Hini  = (float*)(ws + 291 * MiB);// ends 292 MiB

  float* xout = (float*)d_out;
  float* hout = xout + (size_t)kM * kD;
  float* x1 = Abuf;

  // merged weight transpose: 2048+8192+1024+1024+4096 = 16384 blocks
  wtrans_all<<<16384, dim3(32, 8), 0, stream>>>(
      w_ln_z, w_dt, w_fca, w_fc, w_yact, w_y, w_out,
      wzdT, wfgT, wyaT, wyT, woutT);

  rmsnorm_kernel<<<kM, 256, 0, stream>>>(x, g_sio, xn);

  // paired z|dt GEMM -> A = sigm(-dt) [f32], Bv = sigm(z)*sigm(dt) [bf16]
  gemm256<7><<<dim3(2048 / 256, kM / 256), 512, 0, stream>>>(
      xn, wzdT, b_ln_z, b_dt, nullptr, 0, nullptr, Abuf, nullptr, Bvbuf, kM, 2048, kD);
  // ya = xn @ w_y_act + b (bf16)
  gemm256<5><<<dim3(kD / 256, kM / 256), 512, 0, stream>>>(
      xn, wyaT, b_yact, nullptr, nullptr, 0, nullptr, nullptr, yabuf, nullptr, kM, kD, kD);

  scan_phase1<<<dim3(kD / 256, kNC, kB), 256, 0, stream>>>(Abuf, Bvbuf, Pbuf, Sbuf);
  scan_phase2<<<dim3(kD / 256, kB), 256, 0, stream>>>(Pbuf, Sbuf, hidden, Hini);
  scan_phase3<<<dim3(kD / 256, kNC, kB), 256, 0, stream>>>(Abuf, Bvbuf, Hini, hout, hbf);

  // x1 = (h @ w_y + b_y) * silu(ya) + x   (x1 reuses Abuf)
  gemm256<2><<<dim3(kD / 256, kM / 256), 512, 0, stream>>>(
      hbf, wyT, b_y, nullptr, yabuf, kD, x, x1, nullptr, nullptr, kM, kD, kD);

  rmsnorm_kernel<<<kM, 256, 0, stream>>>(x1, g_ffn, xn);

  // paired FFN up+gate: U = fc * silu(fca) — MODE6 specialist kernel
  gemm_ffn<<<dim3(8192 / 128, kM / 256), 512, 0, stream>>>(
      xn, wfgT, b_fca, b_fc, Ubuf, kM, 8192, kD);

  // xout = U @ w_out + b_out + x1  (K=4096)
  gemm256<4><<<dim3(kD / 256, kM / 256), 512, 0, stream>>>(
      Ubuf, woutT, b_out, nullptr, nullptr, 0, x1, xout, nullptr, nullptr, kM, kD, kFF);
}

// Round 14
// 731.813 us; speedup vs baseline: 1.1127x; 1.0009x over previous
//
#include <hip/hip_runtime.h>
#include <stdint.h>

using u16 = unsigned short;
typedef __attribute__((ext_vector_type(8))) __bf16 bf16x8;
typedef __attribute__((ext_vector_type(4))) float f32x4;

#define DEV __device__ __forceinline__

static constexpr int kB = 4, kL = 4096, kD = 1024, kFF = 4096;
static constexpr int kM = kB * kL;
static constexpr int kLC = 256, kNC = kL / kLC;
static constexpr float kEPS = 1e-6f;

DEV u16 f2bf(float v) {
  union { float f; uint32_t u; } x; x.f = v;
  uint32_t r = x.u + 0x7FFFu + ((x.u >> 16) & 1u);  // RNE
  return (u16)(r >> 16);
}
DEV float bf2f(u16 u) {
  union { uint32_t u; float f; } x; x.u = (uint32_t)u << 16; return x.f;
}
DEV float sigm(float x) { return 1.0f / (1.0f + __expf(-x)); }

DEV void gload_lds16(const void* g, void* l) {
  __builtin_amdgcn_global_load_lds(
      (const __attribute__((address_space(1))) void*)g,
      (__attribute__((address_space(3))) void*)l, 16, 0, 0);
}

// ---------------- merged weight transpose + f32->bf16 (all 5 weights, 1 launch)
__global__ __launch_bounds__(256) void wtrans_all(
    const float* __restrict__ w_ln_z, const float* __restrict__ w_dt,
    const float* __restrict__ w_fca, const float* __restrict__ w_fc,
    const float* __restrict__ w_yact, const float* __restrict__ w_y,
    const float* __restrict__ w_out_,
    u16* __restrict__ wzdT, u16* __restrict__ wfgT, u16* __restrict__ wyaT,
    u16* __restrict__ wyT, u16* __restrict__ woutT) {
  const int bid = blockIdx.x;
  const float *a, *b; u16* out; int K, Ncols, bx, local; bool pair;
  if (bid < 2048)       { local = bid;         a = w_ln_z; b = w_dt; out = wzdT;  K = 1024; Ncols = 1024; bx = 64;  pair = true;  }
  else if (bid < 10240) { local = bid - 2048;  a = w_fca;  b = w_fc; out = wfgT;  K = 1024; Ncols = 4096; bx = 256; pair = true;  }
  else if (bid < 11264) { local = bid - 10240; a = w_yact; b = nullptr; out = wyaT; K = 1024; Ncols = 1024; bx = 32; pair = false; }
  else if (bid < 12288) { local = bid - 11264; a = w_y;    b = nullptr; out = wyT;  K = 1024; Ncols = 1024; bx = 32; pair = false; }
  else                  { local = bid - 12288; a = w_out_; b = nullptr; out = woutT; K = 4096; Ncols = 1024; bx = 32; pair = false; }
  const int n0 = (local % bx) * 32, k0 = (local / bx) * 32;
  __shared__ float t[32][33];
  const int tx = threadIdx.x, ty = threadIdx.y;
  const float* src; int c0;
  if (pair) { src = ((n0 >> 5) & 1) ? b : a; c0 = (n0 >> 6) * 32; }
  else      { src = a; c0 = n0; }
#pragma unroll
  for (int i = 0; i < 4; ++i)
    t[ty + i * 8][tx] = src[(size_t)(k0 + ty + i * 8) * Ncols + (c0 + tx)];
  __syncthreads();
#pragma unroll
  for (int i = 0; i < 4; ++i)
    out[(size_t)(n0 + ty + i * 8) * K + (k0 + tx)] = f2bf(t[tx][ty + i * 8]);
}

// ---------------- RMSNorm (f32 in, bf16 out), one block per row, D=1024
__global__ __launch_bounds__(256) void rmsnorm_kernel(const float* __restrict__ x,
                                                      const float* __restrict__ g,
                                                      u16* __restrict__ out) {
  const int row = blockIdx.x;
  const int t = threadIdx.x;
  const float4 v = ((const float4*)(x + (size_t)row * kD))[t];
  float ss = v.x * v.x + v.y * v.y + v.z * v.z + v.w * v.w;
#pragma unroll
  for (int o = 1; o < 64; o <<= 1) ss += __shfl_xor(ss, o, 64);
  __shared__ float red[4];
  if ((t & 63) == 0) red[t >> 6] = ss;
  __syncthreads();
  const float tot = red[0] + red[1] + red[2] + red[3];
  const float sc = rsqrtf(tot * (1.0f / kD) + kEPS);
  const float4 gv = ((const float4*)g)[t];
  const uint32_t lo = (uint32_t)f2bf(v.x * sc * gv.x) | ((uint32_t)f2bf(v.y * sc * gv.y) << 16);
  const uint32_t hi = (uint32_t)f2bf(v.z * sc * gv.z) | ((uint32_t)f2bf(v.w * sc * gv.w) << 16);
  *(uint2*)(out + (size_t)row * kD + t * 4) = make_uint2(lo, hi);
}

// ---------------- RMSNorm (bf16 in, bf16 out)
__global__ __launch_bounds__(256) void rmsnorm_b16(const u16* __restrict__ x,
                                                   const float* __restrict__ g,
                                                   u16* __restrict__ out) {
  const int row = blockIdx.x;
  const int t = threadIdx.x;
  const uint2 raw = ((const uint2*)(x + (size_t)row * kD))[t];
  const float v0 = bf2f((u16)(raw.x & 0xffff)), v1 = bf2f((u16)(raw.x >> 16));
  const float v2 = bf2f((u16)(raw.y & 0xffff)), v3 = bf2f((u16)(raw.y >> 16));
  float ss = v0 * v0 + v1 * v1 + v2 * v2 + v3 * v3;
#pragma unroll
  for (int o = 1; o < 64; o <<= 1) ss += __shfl_xor(ss, o, 64);
  __shared__ float red[4];
  if ((t & 63) == 0) red[t >> 6] = ss;
  __syncthreads();
  const float tot = red[0] + red[1] + red[2] + red[3];
  const float sc = rsqrtf(tot * (1.0f / kD) + kEPS);
  const float4 gv = ((const float4*)g)[t];
  const uint32_t lo = (uint32_t)f2bf(v0 * sc * gv.x) | ((uint32_t)f2bf(v1 * sc * gv.y) << 16);
  const uint32_t hi = (uint32_t)f2bf(v2 * sc * gv.z) | ((uint32_t)f2bf(v3 * sc * gv.w) << 16);
  *(uint2*)(out + (size_t)row * kD + t * 4) = make_uint2(lo, hi);
}

// ---------------- CHAMPION: 256x256 lockstep 4-phase GEMM, spread staging,
// vmcnt(2). K-loop byte-identical to round-13.
// MODE 2: Cb = bf16(v*silu(aux) + res)            (y + residual -> x1 bf16)
// MODE 5: Cb = bf16(v)
// MODE 7: pair coeffs + FUSED chunk-scan: Cf=sigm(-v2) [f32], C2b=bf16(sigm(v1)sigm(v2));
//         epilogue also computes per-chunk (P,S) (block == one 256-step scan chunk)
// MODE 8: Cf = v + bf2f(aux)                       (final out, bf16 residual)
template <int MODE>
__global__ __launch_bounds__(512) void gemm256(
    const u16* __restrict__ A, const u16* __restrict__ Bt,
    const float* __restrict__ bias, const float* __restrict__ bias2,
    const u16* __restrict__ aux, int auxld,
    const float* __restrict__ res, float* __restrict__ Cf,
    u16* __restrict__ Cb, u16* __restrict__ C2b,
    float* __restrict__ Pg, float* __restrict__ Sg,
    int M, int N, int K) {
  __shared__ u16 sm[65536];  // 128 KiB
  const int tid = threadIdx.x;
  const int lane = tid & 63;
  const int wave = tid >> 6;
  const int wr = wave >> 2, wc = wave & 3;  // 2 x 4 wave grid

  // bijective XCD swizzle (m204)
  const int gx = gridDim.x;
  const int nwg = gx * gridDim.y;
  const int bid = blockIdx.y * gx + blockIdx.x;
  const int q = nwg >> 3, r = nwg & 7;
  const int xcd = bid & 7, idx0 = bid >> 3;
  const int wg = (xcd < r ? xcd * (q + 1) : r * (q + 1) + (xcd - r) * q) + idx0;
  const int m0 = (wg / gx) * 256, n0 = (wg % gx) * 256;

  const int NK = K >> 6;

  const int l8 = lane >> 3, l7 = lane & 7;
  const int rsub = wave * 8 + l8;
  const int kel = (l7 ^ l8) * 8;
  const size_t srcA = (size_t)(m0 + rsub) * K + kel;
  const size_t srcB = (size_t)(n0 + rsub) * K + kel;

  auto stage_half = [&](int kt, int half) {
    const int bsel = (kt & 1) * 32768;
    if (half < 2) {
      u16* d = sm + bsel + tid * 8 + half * 8192;
      const u16* s = A + srcA + (size_t)kt * 64 + (size_t)(half * 2) * 64 * K;
      gload_lds16(s, d);
      gload_lds16(s + (size_t)64 * K, d + 4096);
    } else {
      const int hh = half - 2;
      u16* d = sm + bsel + 16384 + tid * 8 + hh * 8192;
      const u16* s = Bt + srcB + (size_t)kt * 64 + (size_t)(hh * 2) * 64 * K;
      gload_lds16(s, d);
      gload_lds16(s + (size_t)64 * K, d + 4096);
    }
  };

  const int ra = lane & 15;
  const int kx0 = ((lane >> 4) ^ l7) * 8;
  const int kx1 = (((lane >> 4) + 4) ^ l7) * 8;

  f32x4 acc[8][4] = {};
  bf16x8 al[4][2], ah[4][2], bl[2][2], bh[2][2];

  stage_half(0, 0); stage_half(0, 1); stage_half(0, 2); stage_half(0, 3);
  stage_half(1, 0);
  asm volatile("s_waitcnt vmcnt(2)");
  asm volatile("s_barrier" ::: "memory");

  for (int h = 0; h < NK; ++h) {
    const u16* as = sm + (h & 1) * 32768 + (wr * 128 + ra) * 64;
    const u16* bs = sm + (h & 1) * 32768 + 16384 + (wc * 64 + ra) * 64;

    // ---- Phase 1: read A-lo + B-lo; stage (h+1,#1)
#pragma unroll
    for (int mi = 0; mi < 4; ++mi) {
      al[mi][0] = *(const bf16x8*)(as + mi * 16 * 64 + kx0);
      al[mi][1] = *(const bf16x8*)(as + mi * 16 * 64 + kx1);
    }
#pragma unroll
    for (int ni = 0; ni < 2; ++ni) {
      bl[ni][0] = *(const bf16x8*)(bs + ni * 16 * 64 + kx0);
      bl[ni][1] = *(const bf16x8*)(bs + ni * 16 * 64 + kx1);
    }
    if (h + 1 < NK) stage_half(h + 1, 1);
    asm volatile("s_barrier" ::: "memory");
    asm volatile("s_waitcnt lgkmcnt(0)");
    __builtin_amdgcn_s_setprio(1);
#pragma unroll
    for (int mi = 0; mi < 4; ++mi)
#pragma unroll
      for (int ni = 0; ni < 2; ++ni)
#pragma unroll
        for (int kk = 0; kk < 2; ++kk)
          acc[mi][ni] = __builtin_amdgcn_mfma_f32_16x16x32_bf16(al[mi][kk], bl[ni][kk], acc[mi][ni], 0, 0, 0);
    __builtin_amdgcn_s_setprio(0);
    asm volatile("s_barrier" ::: "memory");

    // ---- Phase 2: read B-hi; stage (h+1,#2)
#pragma unroll
    for (int ni = 0; ni < 2; ++ni) {
      bh[ni][0] = *(const bf16x8*)(bs + (32 + ni * 16) * 64 + kx0);
      bh[ni][1] = *(const bf16x8*)(bs + (32 + ni * 16) * 64 + kx1);
    }
    if (h + 1 < NK) stage_half(h + 1, 2);
    asm volatile("s_barrier" ::: "memory");
    asm volatile("s_waitcnt lgkmcnt(0)");
    __builtin_amdgcn_s_setprio(1);
#pragma unroll
    for (int mi = 0; mi < 4; ++mi)
#pragma unroll
      for (int ni = 0; ni < 2; ++ni)
#pragma unroll
        for (int kk = 0; kk < 2; ++kk)
          acc[mi][2 + ni] = __builtin_amdgcn_mfma_f32_16x16x32_bf16(al[mi][kk], bh[ni][kk], acc[mi][2 + ni], 0, 0, 0);
    __builtin_amdgcn_s_setprio(0);
    asm volatile("s_barrier" ::: "memory");

    // ---- Phase 3: read A-hi; stage (h+1,#3)
#pragma unroll
    for (int mi = 0; mi < 4; ++mi) {
      ah[mi][0] = *(const bf16x8*)(as + (64 + mi * 16) * 64 + kx0);
      ah[mi][1] = *(const bf16x8*)(as + (64 + mi * 16) * 64 + kx1);
    }
    if (h + 1 < NK) stage_half(h + 1, 3);
    asm volatile("s_barrier" ::: "memory");
    asm volatile("s_waitcnt lgkmcnt(0)");
    __builtin_amdgcn_s_setprio(1);
#pragma unroll
    for (int mi = 0; mi < 4; ++mi)
#pragma unroll
      for (int ni = 0; ni < 2; ++ni)
#pragma unroll
        for (int kk = 0; kk < 2; ++kk)
          acc[4 + mi][ni] = __builtin_amdgcn_mfma_f32_16x16x32_bf16(ah[mi][kk], bl[ni][kk], acc[4 + mi][ni], 0, 0, 0);
    __builtin_amdgcn_s_setprio(0);
    asm volatile("s_barrier" ::: "memory");

    // ---- Phase 4: stage (h+2,#0); MFMA hi x hi; counted vmcnt; barrier
    if (h + 2 < NK) stage_half(h + 2, 0);
    asm volatile("s_barrier" ::: "memory");
    __builtin_amdgcn_s_setprio(1);
#pragma unroll
    for (int mi = 0; mi < 4; ++mi)
#pragma unroll
      for (int ni = 0; ni < 2; ++ni)
#pragma unroll
        for (int kk = 0; kk < 2; ++kk)
          acc[4 + mi][2 + ni] = __builtin_amdgcn_mfma_f32_16x16x32_bf16(ah[mi][kk], bh[ni][kk], acc[4 + mi][2 + ni], 0, 0, 0);
    __builtin_amdgcn_s_setprio(0);
    if (h + 2 < NK) asm volatile("s_waitcnt vmcnt(2)");
    else            asm volatile("s_waitcnt vmcnt(0)");
    asm volatile("s_barrier" ::: "memory");
  }

  // ---- epilogue. C/D layout: col = lane&15, row = (lane>>4)*4 + j
  const int ca = ra;
  const int rq = (lane >> 4) * 4;
  if (MODE == 7) {
    const int Nout = N >> 1;
    // fused chunk-scan accumulators per ni-column (l-order: wr,mi,q,j)
    float Pacc[2] = {1.f, 1.f}, Sacc[2] = {0.f, 0.f};
#pragma unroll
    for (int mi = 0; mi < 8; ++mi) {
#pragma unroll
      for (int ni = 0; ni < 2; ++ni) {
        const int cout = (n0 >> 1) + wc * 32 + ni * 16 + ca;
        const float b1 = bias[cout], b2 = bias2[cout];
        float pj = 1.f, sj = 0.f;
#pragma unroll
        for (int j = 0; j < 4; ++j) {
          const int rr = m0 + wr * 128 + mi * 16 + rq + j;
          const size_t idx = (size_t)rr * Nout + cout;
          const float v1 = acc[mi][ni][j] + b1;
          const float v2 = acc[mi][2 + ni][j] + b2;
          const float Aa = sigm(-v2);
          const float Bb = sigm(v1) * sigm(v2);
          Cf[idx] = Aa;             // decay A (f32)
          C2b[idx] = f2bf(Bb);      // input B (bf16)
          pj *= Aa;
          sj = fmaf(Aa, sj, Bb);    // j ascending
        }
        // q-combine (lanes c15 + 16q, q ascending): seg combine (p1p2, s2+p2*s1)
        float P16 = 1.f, S16 = 0.f;
#pragma unroll
        for (int qq = 0; qq < 4; ++qq) {
          const float pq = __shfl(pj, ca + qq * 16, 64);
          const float sq = __shfl(sj, ca + qq * 16, 64);
          P16 *= pq;
          S16 = fmaf(pq, S16, sq);
        }
        // mi-fold (ascending)
        Sacc[ni] = fmaf(P16, Sacc[ni], S16);
        Pacc[ni] *= P16;
      }
    }
    // wr-fold via LDS (wr=0 earlier); sm safe to reuse after final K-loop barrier
    float* smF = (float*)sm;   // [2][128] P then [2][128] S = 2 KB
    __syncthreads();
    if ((lane >> 4) == 0) {
#pragma unroll
      for (int ni = 0; ni < 2; ++ni) {
        const int col = wc * 32 + ni * 16 + ca;
        smF[wr * 128 + col] = Pacc[ni];
        smF[256 + wr * 128 + col] = Sacc[ni];
      }
    }
    __syncthreads();
    if (wr == 0 && (lane >> 4) == 0) {
      const int bb = m0 >> 12, cc = (m0 & 4095) >> 8;
#pragma unroll
      for (int ni = 0; ni < 2; ++ni) {
        const int col = wc * 32 + ni * 16 + ca;
        const float P0 = smF[col],       P1 = smF[128 + col];
        const float S0 = smF[256 + col], S1 = smF[256 + 128 + col];
        const size_t o = ((size_t)bb * kNC + cc) * kD + ((n0 >> 1) + col);
        Pg[o] = P0 * P1;
        Sg[o] = fmaf(P1, S0, S1);
      }
    }
  } else {
#pragma unroll
    for (int mi = 0; mi < 8; ++mi) {
#pragma unroll
      for (int ni = 0; ni < 4; ++ni) {
        const int c = n0 + wc * 64 + ni * 16 + ca;
        const float bz = bias[c];
#pragma unroll
        for (int j = 0; j < 4; ++j) {
          const int rr = m0 + wr * 128 + mi * 16 + rq + j;
          const size_t idx = (size_t)rr * N + c;
          const float v = acc[mi][ni][j] + bz;
          if (MODE == 2) {
            const float a = bf2f(aux[(size_t)rr * auxld + c]);
            Cb[idx] = f2bf(v * (a * sigm(a)) + res[idx]);   // x1 as bf16
          } else if (MODE == 8) {
            Cf[idx] = v + bf2f(aux[(size_t)rr * auxld + c]); // + bf16 residual
          } else {  // MODE 5
            Cb[idx] = f2bf(v);
          }
        }
      }
    }
  }
}

// ---------------- MODE6 specialist (256x128, 2 blocks/CU, 0 conflicts)
__global__ __launch_bounds__(512, 4) void gemm_ffn(
    const u16* __restrict__ A, const u16* __restrict__ Bt,
    const float* __restrict__ bias, const float* __restrict__ bias2,
    u16* __restrict__ Cb, int M, int N, int K) {
  __shared__ u16 sm[24576];  // 48 KiB
  const int tid = threadIdx.x;
  const int lane = tid & 63;
  const int wave = tid >> 6;
  const int wr = wave >> 1, wc = wave & 1;  // 4M x 2N

  const int gx = gridDim.x;
  const int nwg = gx * gridDim.y;
  const int bid = blockIdx.y * gx + blockIdx.x;
  const int q = nwg >> 3, r = nwg & 7;
  const int xcd = bid & 7, idx0 = bid >> 3;
  const int wg = (xcd < r ? xcd * (q + 1) : r * (q + 1) + (xcd - r) * q) + idx0;
  const int per = gridDim.y * 4;
  const int sg = wg / per, srem = wg % per;
  const int m0 = (srem >> 2) * 256;
  const int n0 = (sg * 4 + (srem & 3)) * 128;

  const int NK = K >> 5;

  const int rsub = wave * 16 + (lane >> 2);
  const int kel = ((lane & 3) ^ ((lane >> 3) & 3)) * 8;
  const size_t srcA = (size_t)(m0 + rsub) * K + kel;
  const size_t srcB = (size_t)(n0 + rsub) * K + kel;

  auto stageA = [&](int kt) {
    u16* d = sm + (kt & 1) * 12288 + tid * 8;
    const u16* s = A + srcA + (size_t)kt * 32;
    gload_lds16(s, d);
    gload_lds16(s + (size_t)128 * K, d + 4096);
  };
  auto stageB = [&](int kt) {
    gload_lds16(Bt + srcB + (size_t)kt * 32,
                sm + (kt & 1) * 12288 + 8192 + tid * 8);
  };

  const int ra = lane & 15;
  const int rb = ra * 32 + ((((lane >> 4) ^ (ra >> 1)) & 3) << 3);

  f32x4 acc[4][4] = {};
  bf16x8 af[4], bfr[4];

  stageA(0); stageB(0);
  if (NK > 1) { stageA(1); stageB(1); }
  asm volatile("s_waitcnt vmcnt(3)");
  asm volatile("s_barrier" ::: "memory");

  for (int h = 0; h < NK; ++h) {
    const u16* Az = sm + (h & 1) * 12288 + wr * 2048;
    const u16* Bz = sm + (h & 1) * 12288 + 8192 + wc * 2048;

#pragma unroll
    for (int mi = 0; mi < 4; ++mi) af[mi] = *(const bf16x8*)(Az + mi * 512 + rb);
    bfr[0] = *(const bf16x8*)(Bz + rb);
    bfr[1] = *(const bf16x8*)(Bz + 512 + rb);
    asm volatile("s_barrier" ::: "memory");
    asm volatile("s_waitcnt lgkmcnt(0)");
    __builtin_amdgcn_s_setprio(1);
#pragma unroll
    for (int mi = 0; mi < 4; ++mi)
#pragma unroll
      for (int ni = 0; ni < 2; ++ni)
        acc[mi][ni] = __builtin_amdgcn_mfma_f32_16x16x32_bf16(af[mi], bfr[ni], acc[mi][ni], 0, 0, 0);
    __builtin_amdgcn_s_setprio(0);
    asm volatile("s_barrier" ::: "memory");

    bfr[2] = *(const bf16x8*)(Bz + 1024 + rb);
    bfr[3] = *(const bf16x8*)(Bz + 1536 + rb);
    if (h + 2 < NK) stageA(h + 2);
    asm volatile("s_barrier" ::: "memory");
    asm volatile("s_waitcnt lgkmcnt(0)");
    __builtin_amdgcn_s_setprio(1);
#pragma unroll
    for (int mi = 0; mi < 4; ++mi)
      acc[mi][2] = __builtin_amdgcn_mfma_f32_16x16x32_bf16(af[mi], bfr[2], acc[mi][2], 0, 0, 0);
    __builtin_amdgcn_s_setprio(0);
    asm volatile("s_barrier" ::: "memory");

    if (h + 2 < NK) stageB(h + 2);
    __builtin_amdgcn_s_setprio(1);
#pragma unroll
    for (int mi = 0; mi < 4; ++mi)
      acc[mi][3] = __builtin_amdgcn_mfma_f32_16x16x32_bf16(af[mi], bfr[3], acc[mi][3], 0, 0, 0);
    __builtin_amdgcn_s_setprio(0);
    if (h + 2 < NK) asm volatile("s_waitcnt vmcnt(3)");
    else            asm volatile("s_waitcnt vmcnt(0)");
    asm volatile("s_barrier" ::: "memory");
  }

  // pair epilogue: v1=fca(gate), v2=fc -> Cb = bf16(v2*silu(v1)), Nout=N/2
  const int ca = lane & 15;
  const int rq = (lane >> 4) * 4;
  const int Nout = N >> 1;
#pragma unroll
  for (int mi = 0; mi < 4; ++mi) {
#pragma unroll
    for (int ni = 0; ni < 2; ++ni) {
      const int cout = (n0 >> 1) + wc * 32 + ni * 16 + ca;
      const float b1 = bias[cout], b2 = bias2[cout];
#pragma unroll
      for (int j = 0; j < 4; ++j) {
        const int rr = m0 + wr * 64 + mi * 16 + rq + j;
        const size_t idx = (size_t)rr * Nout + cout;
        const float v1 = acc[mi][ni][j] + b1;
        const float v2 = acc[mi][2 + ni][j] + b2;
        Cb[idx] = f2bf(v2 * (v1 * sigm(v1)));
      }
    }
  }
}

// ---------------- scan (phase1 fused into MODE7 epilogue)
__global__ __launch_bounds__(256) void scan_phase2(const float* __restrict__ P,
                                                   const float* __restrict__ S,
                                                   const float* __restrict__ hidden,
                                                   float* __restrict__ Hini) {
  const int d = blockIdx.x * 256 + threadIdx.x;
  const int b = blockIdx.y;
  float carry = hidden[(size_t)b * kD + d];
  for (int c = 0; c < kNC; ++c) {
    const size_t o = ((size_t)b * kNC + c) * kD + d;
    Hini[o] = carry;
    carry = fmaf(P[o], carry, S[o]);
  }
}

__global__ __launch_bounds__(256) void scan_phase3(const float* __restrict__ Aa,
                                                   const u16* __restrict__ Bv,
                                                   const float* __restrict__ Hini,
                                                   float* __restrict__ Hout,
                                                   u16* __restrict__ Hbf) {
  const int d = blockIdx.x * 256 + threadIdx.x;
  const int c = blockIdx.y, b = blockIdx.z;
  float h = Hini[((size_t)b * kNC + c) * kD + d];
  size_t base = ((size_t)b * kL + (size_t)c * kLC) * kD + d;
#pragma unroll 4
  for (int l = 0; l < kLC; ++l) {
    h = fmaf(Aa[base], h, bf2f(Bv[base]));
    Hout[base] = h;
    Hbf[base] = f2bf(h);
    base += kD;
  }
}

// ---------------- host
extern "C" void kernel_launch(void* const* d_in, const int* in_sizes, int n_in,
                              void* d_out, int out_size, void* d_ws, size_t ws_size,
                              hipStream_t stream) {
  const float* x      = (const float*)d_in[0];
  const float* hidden = (const float*)d_in[1];
  const float* w_ln_z = (const float*)d_in[2];
  const float* b_ln_z = (const float*)d_in[3];
  const float* w_dt   = (const float*)d_in[4];
  const float* b_dt   = (const float*)d_in[5];
  const float* w_y    = (const float*)d_in[6];
  const float* b_y    = (const float*)d_in[7];
  const float* w_yact = (const float*)d_in[8];
  const float* b_yact = (const float*)d_in[9];
  const float* w_fc   = (const float*)d_in[10];
  const float* b_fc   = (const float*)d_in[11];
  const float* w_fca  = (const float*)d_in[12];
  const float* b_fca  = (const float*)d_in[13];
  const float* w_out  = (const float*)d_in[14];
  const float* b_out  = (const float*)d_in[15];
  const float* g_sio  = (const float*)d_in[16];
  const float* g_ffn  = (const float*)d_in[17];

  char* ws = (char*)d_ws;
  const size_t MiB = 1ull << 20;
  u16* wzdT  = (u16*)(ws + 0 * MiB);      // [2048,1024] paired z|dt, 4 MiB
  u16* wyaT  = (u16*)(ws + 4 * MiB);      // 2 MiB
  u16* wyT   = (u16*)(ws + 6 * MiB);      // 2 MiB
  u16* wfgT  = (u16*)(ws + 8 * MiB);      // [8192,1024] paired fca|fc, 16 MiB
  u16* woutT = (u16*)(ws + 24 * MiB);     // [1024,4096] 8 MiB
  u16*   xn    = (u16*)(ws + 33 * MiB);   // [M,D] bf16 32 MiB (reused as xn2)
  u16*   yabuf = (u16*)(ws + 65 * MiB);   // [M,D] bf16 32 MiB
  float* Abuf  = (float*)(ws + 97 * MiB); // [M,D] f32 64 MiB; x1b overlays after scan
  u16*   x1b   = (u16*)(ws + 97 * MiB);   // [M,D] bf16 (overlays dead Abuf)
  u16*   Bvbuf = (u16*)(ws + 161 * MiB);  // [M,D] bf16 32 MiB (dead after scan)
  u16*   hbf   = (u16*)(ws + 225 * MiB);  // [M,D] bf16 32 MiB (dead after y-GEMM)
  u16*   Ubuf  = (u16*)(ws + 161 * MiB);  // [M,FF] bf16 128 MiB, overlays dead Bv/hbf
  float* Pbuf  = (float*)(ws + 289 * MiB);
  float* Sbuf  = (float*)(ws + 290 * MiB);
  float* Hini  = (float*)(ws + 291 * MiB);// ends 292 MiB

  float* xout = (float*)d_out;
  float* hout = xout + (size_t)kM * kD;

  // merged weight transpose: 2048+8192+1024+1024+4096 = 16384 blocks
  wtrans_all<<<16384, dim3(32, 8), 0, stream>>>(
      w_ln_z, w_dt, w_fca, w_fc, w_yact, w_y, w_out,
      wzdT, wfgT, wyaT, wyT, woutT);

  rmsnorm_kernel<<<kM, 256, 0, stream>>>(x, g_sio, xn);

  // paired z|dt GEMM -> A [f32], Bv [bf16], + fused per-chunk (P,S)
  gemm256<7><<<dim3(2048 / 256, kM / 256), 512, 0, stream>>>(
      xn, wzdT, b_ln_z, b_dt, nullptr, 0, nullptr, Abuf, nullptr, Bvbuf,
      Pbuf, Sbuf, kM, 2048, kD);
  // ya = xn @ w_y_act + b (bf16)
  gemm256<5><<<dim3(kD / 256, kM / 256), 512, 0, stream>>>(
      xn, wyaT, b_yact, nullptr, nullptr, 0, nullptr, nullptr, yabuf, nullptr,
      nullptr, nullptr, kM, kD, kD);

  scan_phase2<<<dim3(kD / 256, kB), 256, 0, stream>>>(Pbuf, Sbuf, hidden, Hini);
  scan_phase3<<<dim3(kD / 256, kNC, kB), 256, 0, stream>>>(Abuf, Bvbuf, Hini, hout, hbf);

  // x1 = (h @ w_y + b_y) * silu(ya) + x  -> bf16 (overlays dead Abuf)
  gemm256<2><<<dim3(kD / 256, kM / 256), 512, 0, stream>>>(
      hbf, wyT, b_y, nullptr, yabuf, kD, x, nullptr, x1b, nullptr,
      nullptr, nullptr, kM, kD, kD);

  rmsnorm_b16<<<kM, 256, 0, stream>>>(x1b, g_ffn, xn);

  // paired FFN up+gate: U = fc * silu(fca) — MODE6 specialist kernel
  gemm_ffn<<<dim3(8192 / 128, kM / 256), 512, 0, stream>>>(
      xn, wfgT, b_fca, b_fc, Ubuf, kM, 8192, kD);

  // xout = U @ w_out + b_out + x1b  (K=4096, bf16 residual)
  gemm256<8><<<dim3(kD / 256, kM / 256), 512, 0, stream>>>(
      Ubuf, woutT, b_out, nullptr, x1b, kD, nullptr, xout, nullptr, nullptr,
      nullptr, nullptr, kM, kD, kFF);
}

// Round 15
// 725.644 us; speedup vs baseline: 1.1222x; 1.0085x over previous
//
#include <hip/hip_runtime.h>
#include <stdint.h>

using u16 = unsigned short;
typedef __attribute__((ext_vector_type(8))) __bf16 bf16x8;
typedef __attribute__((ext_vector_type(4))) float f32x4;

#define DEV __device__ __forceinline__

static constexpr int kB = 4, kL = 4096, kD = 1024, kFF = 4096;
static constexpr int kM = kB * kL;
static constexpr int kLC = 256, kNC = kL / kLC;
static constexpr float kEPS = 1e-6f;

DEV u16 f2bf(float v) {
  union { float f; uint32_t u; } x; x.f = v;
  uint32_t r = x.u + 0x7FFFu + ((x.u >> 16) & 1u);  // RNE
  return (u16)(r >> 16);
}
DEV float bf2f(u16 u) {
  union { uint32_t u; float f; } x; x.u = (uint32_t)u << 16; return x.f;
}
DEV float sigm(float x) { return 1.0f / (1.0f + __expf(-x)); }

DEV void gload_lds16(const void* g, void* l) {
  __builtin_amdgcn_global_load_lds(
      (const __attribute__((address_space(1))) void*)g,
      (__attribute__((address_space(3))) void*)l, 16, 0, 0);
}

// ---------------- merged weight transpose + f32->bf16 (all 5 weights, 1 launch)
__global__ __launch_bounds__(256) void wtrans_all(
    const float* __restrict__ w_ln_z, const float* __restrict__ w_dt,
    const float* __restrict__ w_fca, const float* __restrict__ w_fc,
    const float* __restrict__ w_yact, const float* __restrict__ w_y,
    const float* __restrict__ w_out_,
    u16* __restrict__ wzdT, u16* __restrict__ wfgT, u16* __restrict__ wyaT,
    u16* __restrict__ wyT, u16* __restrict__ woutT) {
  const int bid = blockIdx.x;
  const float *a, *b; u16* out; int K, Ncols, bx, local; bool pair;
  if (bid < 2048)       { local = bid;         a = w_ln_z; b = w_dt; out = wzdT;  K = 1024; Ncols = 1024; bx = 64;  pair = true;  }
  else if (bid < 10240) { local = bid - 2048;  a = w_fca;  b = w_fc; out = wfgT;  K = 1024; Ncols = 4096; bx = 256; pair = true;  }
  else if (bid < 11264) { local = bid - 10240; a = w_yact; b = nullptr; out = wyaT; K = 1024; Ncols = 1024; bx = 32; pair = false; }
  else if (bid < 12288) { local = bid - 11264; a = w_y;    b = nullptr; out = wyT;  K = 1024; Ncols = 1024; bx = 32; pair = false; }
  else                  { local = bid - 12288; a = w_out_; b = nullptr; out = woutT; K = 4096; Ncols = 1024; bx = 32; pair = false; }
  const int n0 = (local % bx) * 32, k0 = (local / bx) * 32;
  __shared__ float t[32][33];
  const int tx = threadIdx.x, ty = threadIdx.y;
  const float* src; int c0;
  if (pair) { src = ((n0 >> 5) & 1) ? b : a; c0 = (n0 >> 6) * 32; }
  else      { src = a; c0 = n0; }
#pragma unroll
  for (int i = 0; i < 4; ++i)
    t[ty + i * 8][tx] = src[(size_t)(k0 + ty + i * 8) * Ncols + (c0 + tx)];
  __syncthreads();
#pragma unroll
  for (int i = 0; i < 4; ++i)
    out[(size_t)(n0 + ty + i * 8) * K + (k0 + tx)] = f2bf(t[tx][ty + i * 8]);
}

// ---------------- RMSNorm (f32 in, bf16 out), one block per row, D=1024
__global__ __launch_bounds__(256) void rmsnorm_kernel(const float* __restrict__ x,
                                                      const float* __restrict__ g,
                                                      u16* __restrict__ out) {
  const int row = blockIdx.x;
  const int t = threadIdx.x;
  const float4 v = ((const float4*)(x + (size_t)row * kD))[t];
  float ss = v.x * v.x + v.y * v.y + v.z * v.z + v.w * v.w;
#pragma unroll
  for (int o = 1; o < 64; o <<= 1) ss += __shfl_xor(ss, o, 64);
  __shared__ float red[4];
  if ((t & 63) == 0) red[t >> 6] = ss;
  __syncthreads();
  const float tot = red[0] + red[1] + red[2] + red[3];
  const float sc = rsqrtf(tot * (1.0f / kD) + kEPS);
  const float4 gv = ((const float4*)g)[t];
  const uint32_t lo = (uint32_t)f2bf(v.x * sc * gv.x) | ((uint32_t)f2bf(v.y * sc * gv.y) << 16);
  const uint32_t hi = (uint32_t)f2bf(v.z * sc * gv.z) | ((uint32_t)f2bf(v.w * sc * gv.w) << 16);
  *(uint2*)(out + (size_t)row * kD + t * 4) = make_uint2(lo, hi);
}

// ---------------- RMSNorm (bf16 in, bf16 out)
__global__ __launch_bounds__(256) void rmsnorm_b16(const u16* __restrict__ x,
                                                   const float* __restrict__ g,
                                                   u16* __restrict__ out) {
  const int row = blockIdx.x;
  const int t = threadIdx.x;
  const uint2 raw = ((const uint2*)(x + (size_t)row * kD))[t];
  const float v0 = bf2f((u16)(raw.x & 0xffff)), v1 = bf2f((u16)(raw.x >> 16));
  const float v2 = bf2f((u16)(raw.y & 0xffff)), v3 = bf2f((u16)(raw.y >> 16));
  float ss = v0 * v0 + v1 * v1 + v2 * v2 + v3 * v3;
#pragma unroll
  for (int o = 1; o < 64; o <<= 1) ss += __shfl_xor(ss, o, 64);
  __shared__ float red[4];
  if ((t & 63) == 0) red[t >> 6] = ss;
  __syncthreads();
  const float tot = red[0] + red[1] + red[2] + red[3];
  const float sc = rsqrtf(tot * (1.0f / kD) + kEPS);
  const float4 gv = ((const float4*)g)[t];
  const uint32_t lo = (uint32_t)f2bf(v0 * sc * gv.x) | ((uint32_t)f2bf(v1 * sc * gv.y) << 16);
  const uint32_t hi = (uint32_t)f2bf(v2 * sc * gv.z) | ((uint32_t)f2bf(v3 * sc * gv.w) << 16);
  *(uint2*)(out + (size_t)row * kD + t * 4) = make_uint2(lo, hi);
}

// ---------------- CHAMPION: 256x256 lockstep 4-phase GEMM (r14, unchanged).
// MODE 2: Cb = bf16(v*silu(aux) + res)
// MODE 5: Cb = bf16(v)
// MODE 7: pair coeffs + fused chunk-scan (P,S)
// MODE 8: Cf = v + bf2f(aux)
template <int MODE>
__global__ __launch_bounds__(512) void gemm256(
    const u16* __restrict__ A, const u16* __restrict__ Bt,
    const float* __restrict__ bias, const float* __restrict__ bias2,
    const u16* __restrict__ aux, int auxld,
    const float* __restrict__ res, float* __restrict__ Cf,
    u16* __restrict__ Cb, u16* __restrict__ C2b,
    float* __restrict__ Pg, float* __restrict__ Sg,
    int M, int N, int K) {
  __shared__ u16 sm[65536];  // 128 KiB
  const int tid = threadIdx.x;
  const int lane = tid & 63;
  const int wave = tid >> 6;
  const int wr = wave >> 2, wc = wave & 3;  // 2 x 4 wave grid

  // bijective XCD swizzle (m204)
  const int gx = gridDim.x;
  const int nwg = gx * gridDim.y;
  const int bid = blockIdx.y * gx + blockIdx.x;
  const int q = nwg >> 3, r = nwg & 7;
  const int xcd = bid & 7, idx0 = bid >> 3;
  const int wg = (xcd < r ? xcd * (q + 1) : r * (q + 1) + (xcd - r) * q) + idx0;
  const int m0 = (wg / gx) * 256, n0 = (wg % gx) * 256;

  const int NK = K >> 6;

  const int l8 = lane >> 3, l7 = lane & 7;
  const int rsub = wave * 8 + l8;
  const int kel = (l7 ^ l8) * 8;
  const size_t srcA = (size_t)(m0 + rsub) * K + kel;
  const size_t srcB = (size_t)(n0 + rsub) * K + kel;

  auto stage_half = [&](int kt, int half) {
    const int bsel = (kt & 1) * 32768;
    if (half < 2) {
      u16* d = sm + bsel + tid * 8 + half * 8192;
      const u16* s = A + srcA + (size_t)kt * 64 + (size_t)(half * 2) * 64 * K;
      gload_lds16(s, d);
      gload_lds16(s + (size_t)64 * K, d + 4096);
    } else {
      const int hh = half - 2;
      u16* d = sm + bsel + 16384 + tid * 8 + hh * 8192;
      const u16* s = Bt + srcB + (size_t)kt * 64 + (size_t)(hh * 2) * 64 * K;
      gload_lds16(s, d);
      gload_lds16(s + (size_t)64 * K, d + 4096);
    }
  };

  const int ra = lane & 15;
  const int kx0 = ((lane >> 4) ^ l7) * 8;
  const int kx1 = (((lane >> 4) + 4) ^ l7) * 8;

  f32x4 acc[8][4] = {};
  bf16x8 al[4][2], ah[4][2], bl[2][2], bh[2][2];

  stage_half(0, 0); stage_half(0, 1); stage_half(0, 2); stage_half(0, 3);
  stage_half(1, 0);
  asm volatile("s_waitcnt vmcnt(2)");
  asm volatile("s_barrier" ::: "memory");

  for (int h = 0; h < NK; ++h) {
    const u16* as = sm + (h & 1) * 32768 + (wr * 128 + ra) * 64;
    const u16* bs = sm + (h & 1) * 32768 + 16384 + (wc * 64 + ra) * 64;

    // ---- Phase 1: read A-lo + B-lo; stage (h+1,#1)
#pragma unroll
    for (int mi = 0; mi < 4; ++mi) {
      al[mi][0] = *(const bf16x8*)(as + mi * 16 * 64 + kx0);
      al[mi][1] = *(const bf16x8*)(as + mi * 16 * 64 + kx1);
    }
#pragma unroll
    for (int ni = 0; ni < 2; ++ni) {
      bl[ni][0] = *(const bf16x8*)(bs + ni * 16 * 64 + kx0);
      bl[ni][1] = *(const bf16x8*)(bs + ni * 16 * 64 + kx1);
    }
    if (h + 1 < NK) stage_half(h + 1, 1);
    asm volatile("s_barrier" ::: "memory");
    asm volatile("s_waitcnt lgkmcnt(0)");
    __builtin_amdgcn_s_setprio(1);
#pragma unroll
    for (int mi = 0; mi < 4; ++mi)
#pragma unroll
      for (int ni = 0; ni < 2; ++ni)
#pragma unroll
        for (int kk = 0; kk < 2; ++kk)
          acc[mi][ni] = __builtin_amdgcn_mfma_f32_16x16x32_bf16(al[mi][kk], bl[ni][kk], acc[mi][ni], 0, 0, 0);
    __builtin_amdgcn_s_setprio(0);
    asm volatile("s_barrier" ::: "memory");

    // ---- Phase 2: read B-hi; stage (h+1,#2)
#pragma unroll
    for (int ni = 0; ni < 2; ++ni) {
      bh[ni][0] = *(const bf16x8*)(bs + (32 + ni * 16) * 64 + kx0);
      bh[ni][1] = *(const bf16x8*)(bs + (32 + ni * 16) * 64 + kx1);
    }
    if (h + 1 < NK) stage_half(h + 1, 2);
    asm volatile("s_barrier" ::: "memory");
    asm volatile("s_waitcnt lgkmcnt(0)");
    __builtin_amdgcn_s_setprio(1);
#pragma unroll
    for (int mi = 0; mi < 4; ++mi)
#pragma unroll
      for (int ni = 0; ni < 2; ++ni)
#pragma unroll
        for (int kk = 0; kk < 2; ++kk)
          acc[mi][2 + ni] = __builtin_amdgcn_mfma_f32_16x16x32_bf16(al[mi][kk], bh[ni][kk], acc[mi][2 + ni], 0, 0, 0);
    __builtin_amdgcn_s_setprio(0);
    asm volatile("s_barrier" ::: "memory");

    // ---- Phase 3: read A-hi; stage (h+1,#3)
#pragma unroll
    for (int mi = 0; mi < 4; ++mi) {
      ah[mi][0] = *(const bf16x8*)(as + (64 + mi * 16) * 64 + kx0);
      ah[mi][1] = *(const bf16x8*)(as + (64 + mi * 16) * 64 + kx1);
    }
    if (h + 1 < NK) stage_half(h + 1, 3);
    asm volatile("s_barrier" ::: "memory");
    asm volatile("s_waitcnt lgkmcnt(0)");
    __builtin_amdgcn_s_setprio(1);
#pragma unroll
    for (int mi = 0; mi < 4; ++mi)
#pragma unroll
      for (int ni = 0; ni < 2; ++ni)
#pragma unroll
        for (int kk = 0; kk < 2; ++kk)
          acc[4 + mi][ni] = __builtin_amdgcn_mfma_f32_16x16x32_bf16(ah[mi][kk], bl[ni][kk], acc[4 + mi][ni], 0, 0, 0);
    __builtin_amdgcn_s_setprio(0);
    asm volatile("s_barrier" ::: "memory");

    // ---- Phase 4: stage (h+2,#0); MFMA hi x hi; counted vmcnt; barrier
    if (h + 2 < NK) stage_half(h + 2, 0);
    asm volatile("s_barrier" ::: "memory");
    __builtin_amdgcn_s_setprio(1);
#pragma unroll
    for (int mi = 0; mi < 4; ++mi)
#pragma unroll
      for (int ni = 0; ni < 2; ++ni)
#pragma unroll
        for (int kk = 0; kk < 2; ++kk)
          acc[4 + mi][2 + ni] = __builtin_amdgcn_mfma_f32_16x16x32_bf16(ah[mi][kk], bh[ni][kk], acc[4 + mi][2 + ni], 0, 0, 0);
    __builtin_amdgcn_s_setprio(0);
    if (h + 2 < NK) asm volatile("s_waitcnt vmcnt(2)");
    else            asm volatile("s_waitcnt vmcnt(0)");
    asm volatile("s_barrier" ::: "memory");
  }

  // ---- epilogue. C/D layout: col = lane&15, row = (lane>>4)*4 + j
  const int ca = ra;
  const int rq = (lane >> 4) * 4;
  if (MODE == 7) {
    const int Nout = N >> 1;
    float Pacc[2] = {1.f, 1.f}, Sacc[2] = {0.f, 0.f};
#pragma unroll
    for (int mi = 0; mi < 8; ++mi) {
#pragma unroll
      for (int ni = 0; ni < 2; ++ni) {
        const int cout = (n0 >> 1) + wc * 32 + ni * 16 + ca;
        const float b1 = bias[cout], b2 = bias2[cout];
        float pj = 1.f, sj = 0.f;
#pragma unroll
        for (int j = 0; j < 4; ++j) {
          const int rr = m0 + wr * 128 + mi * 16 + rq + j;
          const size_t idx = (size_t)rr * Nout + cout;
          const float v1 = acc[mi][ni][j] + b1;
          const float v2 = acc[mi][2 + ni][j] + b2;
          const float Aa = sigm(-v2);
          const float Bb = sigm(v1) * sigm(v2);
          Cf[idx] = Aa;
          C2b[idx] = f2bf(Bb);
          pj *= Aa;
          sj = fmaf(Aa, sj, Bb);
        }
        float P16 = 1.f, S16 = 0.f;
#pragma unroll
        for (int qq = 0; qq < 4; ++qq) {
          const float pq = __shfl(pj, ca + qq * 16, 64);
          const float sq = __shfl(sj, ca + qq * 16, 64);
          P16 *= pq;
          S16 = fmaf(pq, S16, sq);
        }
        Sacc[ni] = fmaf(P16, Sacc[ni], S16);
        Pacc[ni] *= P16;
      }
    }
    float* smF = (float*)sm;
    __syncthreads();
    if ((lane >> 4) == 0) {
#pragma unroll
      for (int ni = 0; ni < 2; ++ni) {
        const int col = wc * 32 + ni * 16 + ca;
        smF[wr * 128 + col] = Pacc[ni];
        smF[256 + wr * 128 + col] = Sacc[ni];
      }
    }
    __syncthreads();
    if (wr == 0 && (lane >> 4) == 0) {
      const int bb = m0 >> 12, cc = (m0 & 4095) >> 8;
#pragma unroll
      for (int ni = 0; ni < 2; ++ni) {
        const int col = wc * 32 + ni * 16 + ca;
        const float P0 = smF[col],       P1 = smF[128 + col];
        const float S0 = smF[256 + col], S1 = smF[256 + 128 + col];
        const size_t o = ((size_t)bb * kNC + cc) * kD + ((n0 >> 1) + col);
        Pg[o] = P0 * P1;
        Sg[o] = fmaf(P1, S0, S1);
      }
    }
  } else {
#pragma unroll
    for (int mi = 0; mi < 8; ++mi) {
#pragma unroll
      for (int ni = 0; ni < 4; ++ni) {
        const int c = n0 + wc * 64 + ni * 16 + ca;
        const float bz = bias[c];
#pragma unroll
        for (int j = 0; j < 4; ++j) {
          const int rr = m0 + wr * 128 + mi * 16 + rq + j;
          const size_t idx = (size_t)rr * N + c;
          const float v = acc[mi][ni][j] + bz;
          if (MODE == 2) {
            const float a = bf2f(aux[(size_t)rr * auxld + c]);
            Cb[idx] = f2bf(v * (a * sigm(a)) + res[idx]);
          } else if (MODE == 8) {
            Cf[idx] = v + bf2f(aux[(size_t)rr * auxld + c]);
          } else {  // MODE 5
            Cb[idx] = f2bf(v);
          }
        }
      }
    }
  }
}

// ---------------- FFN specialist v2: 256x256 4-phase, re-derived staging flight.
// Defect fixed vs champion: its Bhi(h+1) was staged P3 and FORCED by the P4
// vmcnt ~1 phase later (~350cy << 900cy HBM latency) -> per-iter stall.
// Region liveness (each wave reads lo+hi of its own half): A halves die at
// end-P3(s), B halves at end-P2(s). Schedule (1 half = 2 gloads per phase):
//   P1(s): stage Alo(s+1)  [other buf; dead since P3(s-1)]
//   P2(s): stage Ahi(s+1)  [other buf]
//   P3(s): stage Blo(s+2)  [current buf; B region dead after end-P2(s)]
//   P4(s): stage Bhi(s+2); vmcnt(4) -> forces tile s+1 exactly, leaves the
//          two just-issued B(s+2) halves in flight (4-6 phases each).
// Min flight 2.5 phases (~850cy) >= HBM latency. Tail: vmcnt(0).
__global__ __launch_bounds__(512) void gemm_ffn8(
    const u16* __restrict__ A, const u16* __restrict__ Bt,
    const float* __restrict__ bias, const float* __restrict__ bias2,
    u16* __restrict__ Cb, int M, int N, int K) {
  __shared__ u16 sm[65536];
  const int tid = threadIdx.x;
  const int lane = tid & 63;
  const int wave = tid >> 6;
  const int wr = wave >> 2, wc = wave & 3;

  const int gx = gridDim.x;
  const int nwg = gx * gridDim.y;
  const int bid = blockIdx.y * gx + blockIdx.x;
  const int q = nwg >> 3, r = nwg & 7;
  const int xcd = bid & 7, idx0 = bid >> 3;
  const int wg = (xcd < r ? xcd * (q + 1) : r * (q + 1) + (xcd - r) * q) + idx0;
  const int m0 = (wg / gx) * 256, n0 = (wg % gx) * 256;

  const int NK = K >> 6;

  const int l8 = lane >> 3, l7 = lane & 7;
  const int rsub = wave * 8 + l8;
  const int kel = (l7 ^ l8) * 8;
  const size_t srcA = (size_t)(m0 + rsub) * K + kel;
  const size_t srcB = (size_t)(n0 + rsub) * K + kel;

  auto stage_half = [&](int kt, int half) {
    const int bsel = (kt & 1) * 32768;
    if (half < 2) {
      u16* d = sm + bsel + tid * 8 + half * 8192;
      const u16* s = A + srcA + (size_t)kt * 64 + (size_t)(half * 2) * 64 * K;
      gload_lds16(s, d);
      gload_lds16(s + (size_t)64 * K, d + 4096);
    } else {
      const int hh = half - 2;
      u16* d = sm + bsel + 16384 + tid * 8 + hh * 8192;
      const u16* s = Bt + srcB + (size_t)kt * 64 + (size_t)(hh * 2) * 64 * K;
      gload_lds16(s, d);
      gload_lds16(s + (size_t)64 * K, d + 4096);
    }
  };

  const int ra = lane & 15;
  const int kx0 = ((lane >> 4) ^ l7) * 8;
  const int kx1 = (((lane >> 4) + 4) ^ l7) * 8;

  f32x4 acc[8][4] = {};
  bf16x8 al[4][2], ah[4][2], bl[2][2], bh[2][2];

  // prologue: tile 0 complete + B halves of tile 1 (their slots are P3/P4(-1))
  stage_half(0, 0); stage_half(0, 1); stage_half(0, 2); stage_half(0, 3);
  if (NK > 1) {
    stage_half(1, 2); stage_half(1, 3);
    asm volatile("s_waitcnt vmcnt(4)");   // 12 issued, force oldest 8 = tile 0
  } else {
    asm volatile("s_waitcnt vmcnt(0)");
  }
  asm volatile("s_barrier" ::: "memory");

  for (int s = 0; s < NK; ++s) {
    const int bsel = (s & 1) * 32768;
    const u16* as = sm + bsel + (wr * 128 + ra) * 64;
    const u16* bs = sm + bsel + 16384 + (wc * 64 + ra) * 64;

    // ---- P1: read a_lo + b_lo; stage Alo(s+1)
#pragma unroll
    for (int mi = 0; mi < 4; ++mi) {
      al[mi][0] = *(const bf16x8*)(as + mi * 16 * 64 + kx0);
      al[mi][1] = *(const bf16x8*)(as + mi * 16 * 64 + kx1);
    }
#pragma unroll
    for (int ni = 0; ni < 2; ++ni) {
      bl[ni][0] = *(const bf16x8*)(bs + ni * 16 * 64 + kx0);
      bl[ni][1] = *(const bf16x8*)(bs + ni * 16 * 64 + kx1);
    }
    if (s + 1 < NK) stage_half(s + 1, 0);
    asm volatile("s_barrier" ::: "memory");
    asm volatile("s_waitcnt lgkmcnt(0)");
    __builtin_amdgcn_s_setprio(1);
#pragma unroll
    for (int mi = 0; mi < 4; ++mi)
#pragma unroll
      for (int ni = 0; ni < 2; ++ni)
#pragma unroll
        for (int kk = 0; kk < 2; ++kk)
          acc[mi][ni] = __builtin_amdgcn_mfma_f32_16x16x32_bf16(al[mi][kk], bl[ni][kk], acc[mi][ni], 0, 0, 0);
    __builtin_amdgcn_s_setprio(0);
    asm volatile("s_barrier" ::: "memory");

    // ---- P2: read b_hi; stage Ahi(s+1)
#pragma unroll
    for (int ni = 0; ni < 2; ++ni) {
      bh[ni][0] = *(const bf16x8*)(bs + (32 + ni * 16) * 64 + kx0);
      bh[ni][1] = *(const bf16x8*)(bs + (32 + ni * 16) * 64 + kx1);
    }
    if (s + 1 < NK) stage_half(s + 1, 1);
    asm volatile("s_barrier" ::: "memory");
    asm volatile("s_waitcnt lgkmcnt(0)");
    __builtin_amdgcn_s_setprio(1);
#pragma unroll
    for (int mi = 0; mi < 4; ++mi)
#pragma unroll
      for (int ni = 0; ni < 2; ++ni)
#pragma unroll
        for (int kk = 0; kk < 2; ++kk)
          acc[mi][2 + ni] = __builtin_amdgcn_mfma_f32_16x16x32_bf16(al[mi][kk], bh[ni][kk], acc[mi][2 + ni], 0, 0, 0);
    __builtin_amdgcn_s_setprio(0);
    asm volatile("s_barrier" ::: "memory");

    // ---- P3: read a_hi; stage Blo(s+2) [B region of tile s dead after P2]
#pragma unroll
    for (int mi = 0; mi < 4; ++mi) {
      ah[mi][0] = *(const bf16x8*)(as + (64 + mi * 16) * 64 + kx0);
      ah[mi][1] = *(const bf16x8*)(as + (64 + mi * 16) * 64 + kx1);
    }
    if (s + 2 < NK) stage_half(s + 2, 2);
    asm volatile("s_barrier" ::: "memory");
    asm volatile("s_waitcnt lgkmcnt(0)");
    __builtin_amdgcn_s_setprio(1);
#pragma unroll
    for (int mi = 0; mi < 4; ++mi)
#pragma unroll
      for (int ni = 0; ni < 2; ++ni)
#pragma unroll
        for (int kk = 0; kk < 2; ++kk)
          acc[4 + mi][ni] = __builtin_amdgcn_mfma_f32_16x16x32_bf16(ah[mi][kk], bl[ni][kk], acc[4 + mi][ni], 0, 0, 0);
    __builtin_amdgcn_s_setprio(0);
    asm volatile("s_barrier" ::: "memory");

    // ---- P4: stage Bhi(s+2); MFMA hi x hi; vmcnt(4); barrier
    if (s + 2 < NK) stage_half(s + 2, 3);
    asm volatile("s_barrier" ::: "memory");
    __builtin_amdgcn_s_setprio(1);
#pragma unroll
    for (int mi = 0; mi < 4; ++mi)
#pragma unroll
      for (int ni = 0; ni < 2; ++ni)
#pragma unroll
        for (int kk = 0; kk < 2; ++kk)
          acc[4 + mi][2 + ni] = __builtin_amdgcn_mfma_f32_16x16x32_bf16(ah[mi][kk], bh[ni][kk], acc[4 + mi][2 + ni], 0, 0, 0);
    __builtin_amdgcn_s_setprio(0);
    if (s + 2 < NK) asm volatile("s_waitcnt vmcnt(4)");  // tile s+1 forced; B(s+2) stays in flight
    else            asm volatile("s_waitcnt vmcnt(0)");  // tail drain
    asm volatile("s_barrier" ::: "memory");
  }

  // pair epilogue: v1=fca(gate), v2=fc -> Cb = bf16(v2*silu(v1)), Nout=N/2
  const int ca = ra;
  const int rq = (lane >> 4) * 4;
  const int Nout = N >> 1;
#pragma unroll
  for (int mi = 0; mi < 8; ++mi) {
#pragma unroll
    for (int ni = 0; ni < 2; ++ni) {
      const int cout = (n0 >> 1) + wc * 32 + ni * 16 + ca;
      const float b1 = bias[cout], b2 = bias2[cout];
#pragma unroll
      for (int j = 0; j < 4; ++j) {
        const int rr = m0 + wr * 128 + mi * 16 + rq + j;
        const size_t idx = (size_t)rr * Nout + cout;
        const float v1 = acc[mi][ni][j] + b1;
        const float v2 = acc[mi][2 + ni][j] + b2;
        Cb[idx] = f2bf(v2 * (v1 * sigm(v1)));
      }
    }
  }
}

// ---------------- scan (phase1 fused into MODE7 epilogue)
__global__ __launch_bounds__(256) void scan_phase2(const float* __restrict__ P,
                                                   const float* __restrict__ S,
                                                   const float* __restrict__ hidden,
                                                   float* __restrict__ Hini) {
  const int d = blockIdx.x * 256 + threadIdx.x;
  const int b = blockIdx.y;
  float carry = hidden[(size_t)b * kD + d];
  for (int c = 0; c < kNC; ++c) {
    const size_t o = ((size_t)b * kNC + c) * kD + d;
    Hini[o] = carry;
    carry = fmaf(P[o], carry, S[o]);
  }
}

__global__ __launch_bounds__(256) void scan_phase3(const float* __restrict__ Aa,
                                                   const u16* __restrict__ Bv,
                                                   const float* __restrict__ Hini,
                                                   float* __restrict__ Hout,
                                                   u16* __restrict__ Hbf) {
  const int d = blockIdx.x * 256 + threadIdx.x;
  const int c = blockIdx.y, b = blockIdx.z;
  float h = Hini[((size_t)b * kNC + c) * kD + d];
  size_t base = ((size_t)b * kL + (size_t)c * kLC) * kD + d;
#pragma unroll 4
  for (int l = 0; l < kLC; ++l) {
    h = fmaf(Aa[base], h, bf2f(Bv[base]));
    Hout[base] = h;
    Hbf[base] = f2bf(h);
    base += kD;
  }
}

// ---------------- host
extern "C" void kernel_launch(void* const* d_in, const int* in_sizes, int n_in,
                              void* d_out, int out_size, void* d_ws, size_t ws_size,
                              hipStream_t stream) {
  const float* x      = (const float*)d_in[0];
  const float* hidden = (const float*)d_in[1];
  const float* w_ln_z = (const float*)d_in[2];
  const float* b_ln_z = (const float*)d_in[3];
  const float* w_dt   = (const float*)d_in[4];
  const float* b_dt   = (const float*)d_in[5];
  const float* w_y    = (const float*)d_in[6];
  const float* b_y    = (const float*)d_in[7];
  const float* w_yact = (const float*)d_in[8];
  const float* b_yact = (const float*)d_in[9];
  const float* w_fc   = (const float*)d_in[10];
  const float* b_fc   = (const float*)d_in[11];
  const float* w_fca  = (const float*)d_in[12];
  const float* b_fca  = (const float*)d_in[13];
  const float* w_out  = (const float*)d_in[14];
  const float* b_out  = (const float*)d_in[15];
  const float* g_sio  = (const float*)d_in[16];
  const float* g_ffn  = (const float*)d_in[17];

  char* ws = (char*)d_ws;
  const size_t MiB = 1ull << 20;
  u16* wzdT  = (u16*)(ws + 0 * MiB);      // [2048,1024] paired z|dt, 4 MiB
  u16* wyaT  = (u16*)(ws + 4 * MiB);      // 2 MiB
  u16* wyT   = (u16*)(ws + 6 * MiB);      // 2 MiB
  u16* wfgT  = (u16*)(ws + 8 * MiB);      // [8192,1024] paired fca|fc, 16 MiB
  u16* woutT = (u16*)(ws + 24 * MiB);     // [1024,4096] 8 MiB
  u16*   xn    = (u16*)(ws + 33 * MiB);   // [M,D] bf16 32 MiB (reused as xn2)
  u16*   yabuf = (u16*)(ws + 65 * MiB);   // [M,D] bf16 32 MiB
  float* Abuf  = (float*)(ws + 97 * MiB); // [M,D] f32 64 MiB; x1b overlays after scan
  u16*   x1b   = (u16*)(ws + 97 * MiB);   // [M,D] bf16 (overlays dead Abuf)
  u16*   Bvbuf = (u16*)(ws + 161 * MiB);  // [M,D] bf16 32 MiB (dead after scan)
  u16*   hbf   = (u16*)(ws + 225 * MiB);  // [M,D] bf16 32 MiB (dead after y-GEMM)
  u16*   Ubuf  = (u16*)(ws + 161 * MiB);  // [M,FF] bf16 128 MiB, overlays dead Bv/hbf
  float* Pbuf  = (float*)(ws + 289 * MiB);
  float* Sbuf  = (float*)(ws + 290 * MiB);
  float* Hini  = (float*)(ws + 291 * MiB);// ends 292 MiB

  float* xout = (float*)d_out;
  float* hout = xout + (size_t)kM * kD;

  // merged weight transpose: 2048+8192+1024+1024+4096 = 16384 blocks
  wtrans_all<<<16384, dim3(32, 8), 0, stream>>>(
      w_ln_z, w_dt, w_fca, w_fc, w_yact, w_y, w_out,
      wzdT, wfgT, wyaT, wyT, woutT);

  rmsnorm_kernel<<<kM, 256, 0, stream>>>(x, g_sio, xn);

  // paired z|dt GEMM -> A [f32], Bv [bf16], + fused per-chunk (P,S)
  gemm256<7><<<dim3(2048 / 256, kM / 256), 512, 0, stream>>>(
      xn, wzdT, b_ln_z, b_dt, nullptr, 0, nullptr, Abuf, nullptr, Bvbuf,
      Pbuf, Sbuf, kM, 2048, kD);
  // ya = xn @ w_y_act + b (bf16)
  gemm256<5><<<dim3(kD / 256, kM / 256), 512, 0, stream>>>(
      xn, wyaT, b_yact, nullptr, nullptr, 0, nullptr, nullptr, yabuf, nullptr,
      nullptr, nullptr, kM, kD, kD);

  scan_phase2<<<dim3(kD / 256, kB), 256, 0, stream>>>(Pbuf, Sbuf, hidden, Hini);
  scan_phase3<<<dim3(kD / 256, kNC, kB), 256, 0, stream>>>(Abuf, Bvbuf, Hini, hout, hbf);

  // x1 = (h @ w_y + b_y) * silu(ya) + x  -> bf16 (overlays dead Abuf)
  gemm256<2><<<dim3(kD / 256, kM / 256), 512, 0, stream>>>(
      hbf, wyT, b_y, nullptr, yabuf, kD, x, nullptr, x1b, nullptr,
      nullptr, nullptr, kM, kD, kD);

  rmsnorm_b16<<<kM, 256, 0, stream>>>(x1b, g_ffn, xn);

  // paired FFN up+gate: U = fc * silu(fca) — v2 schedule (flight-fixed)
  gemm_ffn8<<<dim3(8192 / 256, kM / 256), 512, 0, stream>>>(
      xn, wfgT, b_fca, b_fc, Ubuf, kM, 8192, kD);

  // xout = U @ w_out + b_out + x1b  (K=4096, bf16 residual)
  gemm256<8><<<dim3(kD / 256, kM / 256), 512, 0, stream>>>(
      Ubuf, woutT, b_out, nullptr, x1b, kD, nullptr, xout, nullptr, nullptr,
      nullptr, nullptr, kM, kD, kFF);
}